// Round 5
// baseline (276.324 us; speedup 1.0000x reference)
//
#include <hip/hip_runtime.h>
#include <stdint.h>

// Problem constants: B=4, T=2048, D=1024, H=16, DH=64
#define B_  4
#define T_  2048
#define D_  1024
#define H_  16
#define DH_ 64

typedef unsigned short u16;
typedef __attribute__((ext_vector_type(8))) short bf16x8;   // 8 bf16 = 4 VGPRs
typedef __attribute__((ext_vector_type(8))) unsigned short u16x8;
typedef __attribute__((ext_vector_type(4))) unsigned short u16x4;
typedef __attribute__((ext_vector_type(4))) float f32x4;

#define NT_ ((size_t)B_ * T_ * D_)          // 8.4M elements
#define QSCALE 0.18033688011112043f         // log2(e)/sqrt(DH): exp2-domain softmax

__device__ __forceinline__ u16 f2bf(float f) {
    union { float f; uint32_t u; } v; v.f = f;
    uint32_t r = v.u + 0x7FFFu + ((v.u >> 16) & 1u);   // RNE
    return (u16)(r >> 16);
}

// pack two fp32 into one dword of 2 bf16 (truncation) — single v_perm_b32
__device__ __forceinline__ uint32_t pack2(float lo, float hi) {
    union { float f; uint32_t u; } a, b; a.f = lo; b.f = hi;
    return __builtin_amdgcn_perm(b.u, a.u, 0x07060302u);
}

// async 16B global->LDS (lds dest is wave-uniform; HW adds lane*16)
__device__ __forceinline__ void gl2lds16(const u16* g, u16* l) {
    __builtin_amdgcn_global_load_lds(
        (const __attribute__((address_space(1))) unsigned int*)g,
        (__attribute__((address_space(3))) unsigned int*)l,
        16, 0, 0);
}

#define VMCNT(n) asm volatile("s_waitcnt vmcnt(" #n ")" ::: "memory")
#define SB0()    __builtin_amdgcn_sched_barrier(0)

// swizzled LDS fragment read: row in element-rows (128B stride), ks selects
// 32-elem K-half, lq*16B within; swzr = (lm&7)<<4 XOR (matches staging layout)
__device__ __forceinline__ bf16x8 ldsrd(const u16* base, int row, int ks,
                                        int lq, int swzr) {
    int off = row * 128 + ks * 64 + lq * 16;   // bytes
    return *(const bf16x8*)((const char*)base + (off ^ swzr));
}

// ---------------------------------------------------------------------------
// fp32 -> bf16 converters
// ---------------------------------------------------------------------------
__global__ __launch_bounds__(256) void cvt_x_kernel(
    const float* __restrict__ src, u16* __restrict__ dst, int n8)
{
    int i = blockIdx.x * 256 + threadIdx.x;
    if (i >= n8) return;
    f32x4 a = ((const f32x4*)src)[2 * i];
    f32x4 b = ((const f32x4*)src)[2 * i + 1];
    u16x8 o;
    o[0]=f2bf(a[0]); o[1]=f2bf(a[1]); o[2]=f2bf(a[2]); o[3]=f2bf(a[3]);
    o[4]=f2bf(b[0]); o[5]=f2bf(b[1]); o[6]=f2bf(b[2]); o[7]=f2bf(b[3]);
    ((u16x8*)dst)[i] = o;
}

__global__ __launch_bounds__(256) void cvt_w_kernel(
    const float* __restrict__ w0, const float* __restrict__ w1,
    const float* __restrict__ w2, const float* __restrict__ w3,
    u16* __restrict__ dst)   // 4 consecutive D*D segments: Wq,Wk,Wv,Wo
{
    const float* src = (blockIdx.y == 0) ? w0 : (blockIdx.y == 1) ? w1
                     : (blockIdx.y == 2) ? w2 : w3;
    u16* d = dst + (size_t)blockIdx.y * (D_ * D_);
    int i = blockIdx.x * 256 + threadIdx.x;
    f32x4 a = ((const f32x4*)src)[2 * i];
    f32x4 b = ((const f32x4*)src)[2 * i + 1];
    u16x8 o;
    o[0]=f2bf(a[0]); o[1]=f2bf(a[1]); o[2]=f2bf(a[2]); o[3]=f2bf(a[3]);
    o[4]=f2bf(b[0]); o[5]=f2bf(b[1]); o[6]=f2bf(b[2]); o[7]=f2bf(b[3]);
    ((u16x8*)d)[i] = o;
}

// ---------------------------------------------------------------------------
// QKV GEMM: 256x192 tile, 8 waves, read-pipelined 4-phase schedule
// (unchanged from round 3 — see comments there; verified working)
// ---------------------------------------------------------------------------
template<int OUT_MODE>
__global__ __launch_bounds__(512) void gemm8_kernel(
    const u16* __restrict__ X, const u16* __restrict__ W,
    void* __restrict__ C, int M, int N, int K)
{
    __shared__ __align__(16) u16 Ab2[2][256 * 64];   // 64 KB
    __shared__ __align__(16) u16 Bb2[2][192 * 64];   // 48 KB

    const int tid  = threadIdx.x;
    const int wave = tid >> 6;
    const int lane = tid & 63;
    const int lq = lane >> 4, lm = lane & 15;
    const int wm = wave >> 2;      // wave's M slot (0..1) -> 128 rows
    const int wn = wave & 3;       // wave's N slot (0..3) -> 48 cols

    // rect XCD swizzle: XCD (bid&7) owns an 8x8 tile rectangle
    const int xcd = (int)blockIdx.x & 7;
    const int idx = (int)blockIdx.x >> 3;   // 0..63
    const int m0 = (((xcd & 3) << 3) + (idx & 7)) << 8;      // 32 M-tiles
    const int n0 = (((xcd >> 2) << 3) + (idx >> 3)) * 192;   // 16 N-tiles

    // staging: each gl2lds covers 64 rows (512thr x 16B = 8KB); 16B chunk
    // scol pre-swizzled so LINEAR LDS DMA writes land in swizzled layout.
    const int srow = wave * 8 + (lane >> 3);                 // 0..63
    const int scol = ((lane & 7) ^ (lane >> 3)) << 3;        // elements
    const u16* gA = X + (size_t)(m0 + srow) * K + scol;
    const u16* gB = W + (size_t)(n0 + srow) * K + scol;
    const size_t rK64 = (size_t)64 * K;

    const int swzr = (lm & 7) << 4;        // ds_read byte-address XOR

    f32x4 acc[8][3] = {};                  // 96 AGPR
    bf16x8 afA[2][2], afB[2][2];           // A frags, ping-pong by phase parity
    bf16x8 bqA[3][2], bqB[3][2];           // B frags, ping-pong by tile parity
    const int NT = K >> 6;                 // 16

    // ---- prologue: stage A0(4), B0(3), B1(3) ----
    gl2lds16(gA,            (u16*)Ab2[0] + wave * 512);
    gl2lds16(gA + rK64,     (u16*)Ab2[0] + 4096  + wave * 512);
    gl2lds16(gA + 2 * rK64, (u16*)Ab2[0] + 8192  + wave * 512);
    gl2lds16(gA + 3 * rK64, (u16*)Ab2[0] + 12288 + wave * 512);
    gl2lds16(gB,            (u16*)Bb2[0] + wave * 512);
    gl2lds16(gB + rK64,     (u16*)Bb2[0] + 4096  + wave * 512);
    gl2lds16(gB + 2 * rK64, (u16*)Bb2[0] + 8192  + wave * 512);
    gl2lds16(gB + 64,            (u16*)Bb2[1] + wave * 512);
    gl2lds16(gB + 64 + rK64,     (u16*)Bb2[1] + 4096  + wave * 512);
    gl2lds16(gB + 64 + 2 * rK64, (u16*)Bb2[1] + 8192  + wave * 512);
    VMCNT(3);                               // A0,B0 landed; B1 (3) in flight
    __builtin_amdgcn_s_barrier();
    // initial frags: tile0 phase0 A + tile0 B
#pragma unroll
    for (int i2 = 0; i2 < 2; ++i2)
#pragma unroll
        for (int ks = 0; ks < 2; ++ks)
            afA[i2][ks] = ldsrd(Ab2[0], wm * 128 + i2 * 16 + lm, ks, lq, swzr);
#pragma unroll
    for (int j = 0; j < 3; ++j)
#pragma unroll
        for (int ks = 0; ks < 2; ++ks)
            bqA[j][ks] = ldsrd(Bb2[0], wn * 48 + j * 16 + lm, ks, lq, swzr);

    // one K-tile; af sets toggle per phase (q0:A, q1:B, q2:A, q3:B), bq sets
    // toggle per tile (all register indices static after inlining).
    auto tile_body = [&](int t, bf16x8 (&bqU)[3][2], bf16x8 (&bqF)[3][2])
        __attribute__((always_inline)) -> void {
        const u16* Ac = Ab2[t & 1];
        const u16* An = Ab2[(t + 1) & 1];
        const u16* Bn = Bb2[(t + 1) & 1];
        u16* Abn = (u16*)Ab2[(t + 1) & 1];
        u16* Bbc = (u16*)Bb2[t & 1];
        const bool stA = (t + 1 < NT);
        const bool stB = (t + 2 < NT);
        const u16* gAs = gA + (size_t)(t + 1) * 64;
        const u16* gBs = gB + (size_t)(t + 2) * 64;

#define MFMA_PH(Q, AF, BQ)                                                  \
        __builtin_amdgcn_s_setprio(1);                                      \
        _Pragma("unroll")                                                   \
        for (int ks = 0; ks < 2; ++ks)                                      \
            _Pragma("unroll")                                               \
            for (int i2 = 0; i2 < 2; ++i2)                                  \
                _Pragma("unroll")                                           \
                for (int j = 0; j < 3; ++j)                                 \
                    acc[2 * (Q) + i2][j] =                                  \
                        __builtin_amdgcn_mfma_f32_16x16x32_bf16(            \
                            AF[i2][ks], BQ[j][ks], acc[2 * (Q) + i2][j],    \
                            0, 0, 0);                                       \
        __builtin_amdgcn_s_setprio(0);

#define RD_AF(SET, P, BASE)                                                 \
        _Pragma("unroll")                                                   \
        for (int i2 = 0; i2 < 2; ++i2)                                      \
            _Pragma("unroll")                                               \
            for (int ks = 0; ks < 2; ++ks)                                  \
                SET[i2][ks] = ldsrd(BASE,                                   \
                    wm * 128 + (2 * (P) + i2) * 16 + lm, ks, lq, swzr);

        // ---- phase 0: uses afA; read afB(p1); stage A[t+1] h0 ----
        RD_AF(afB, 1, Ac);
        if (stA) {
            gl2lds16(gAs,        Abn + wave * 512);
            gl2lds16(gAs + rK64, Abn + 4096 + wave * 512);
        }
        SB0(); __builtin_amdgcn_s_barrier(); SB0();
        MFMA_PH(0, afA, bqU); SB0();
        __builtin_amdgcn_s_barrier();

        // ---- phase 1: uses afB; read afA(p2); stage A[t+1] h1 ----
        RD_AF(afA, 2, Ac);
        if (stA) {
            gl2lds16(gAs + 2 * rK64, Abn + 8192  + wave * 512);
            gl2lds16(gAs + 3 * rK64, Abn + 12288 + wave * 512);
        }
        SB0(); __builtin_amdgcn_s_barrier(); SB0();
        MFMA_PH(1, afB, bqU); SB0();
        __builtin_amdgcn_s_barrier();

        // ---- phase 2: uses afA; read afB(p3); stage B[t+2] c0,c1 ----
        RD_AF(afB, 3, Ac);
        if (stB) {
            gl2lds16(gBs,        Bbc + wave * 512);
            gl2lds16(gBs + rK64, Bbc + 4096 + wave * 512);
        }
        SB0(); __builtin_amdgcn_s_barrier(); SB0();
        MFMA_PH(2, afA, bqU); SB0();
        if (stB)      { VMCNT(2); }   // A[t+1],B[t+1] landed; B[t+2]h0 in flight
        else if (stA) { VMCNT(0); }   // t==NT-2: drain A[NT-1]
        __builtin_amdgcn_s_barrier();

        // ---- phase 3: uses afB; read next-tile afA(p0)+bqF; stage B[t+2] c2 ----
        if (stA) {
            RD_AF(afA, 0, An);
#pragma unroll
            for (int j = 0; j < 3; ++j)
#pragma unroll
                for (int ks = 0; ks < 2; ++ks)
                    bqF[j][ks] = ldsrd(Bn, wn * 48 + j * 16 + lm, ks, lq, swzr);
        }
        if (stB)
            gl2lds16(gBs + 2 * rK64, Bbc + 8192 + wave * 512);
        SB0(); __builtin_amdgcn_s_barrier(); SB0();
        MFMA_PH(3, afB, bqU); SB0();
        __builtin_amdgcn_s_barrier();
#undef RD_AF
#undef MFMA_PH
    };

#pragma unroll 1
    for (int tt = 0; tt < NT; tt += 2) {
        tile_body(tt,     bqA, bqB);
        tile_body(tt + 1, bqB, bqA);
    }

    // ---- epilogue: acc[i][j][r] -> row m0+wm*128+i*16+lq*4+r,
    //                               col n0+wn*48+j*16+lm ----
#pragma unroll
    for (int i = 0; i < 8; ++i)
#pragma unroll
        for (int j = 0; j < 3; ++j) {
            int rowb = m0 + wm * 128 + i * 16 + lq * 4;
            int col  = n0 + wn * 48 + j * 16 + lm;
            if (OUT_MODE == 2) {
#pragma unroll
                for (int r = 0; r < 4; ++r)
                    ((float*)C)[(size_t)(rowb + r) * N + col] = acc[i][j][r];
            } else {
                u16* Qp = (u16*)C;
                int region = col >> 10;      // per-fragment: 192 tile straddles
                int colr = col & 1023;
                if (region == 0) {
#pragma unroll
                    for (int r = 0; r < 4; ++r)
                        Qp[(size_t)(rowb + r) * D_ + colr] = f2bf(acc[i][j][r] * QSCALE);
                } else if (region == 1) {
#pragma unroll
                    for (int r = 0; r < 4; ++r)
                        (Qp + NT_)[(size_t)(rowb + r) * D_ + colr] = f2bf(acc[i][j][r]);
                } else {
                    int b = rowb >> 11, tt2 = rowb & (T_ - 1);   // 4 consecutive t
                    u16x4 pk;
#pragma unroll
                    for (int r = 0; r < 4; ++r) pk[r] = f2bf(acc[i][j][r]);
                    *(u16x4*)((Qp + 2 * NT_) + ((size_t)b * D_ + colr) * T_ + tt2) = pk;
                }
            }
        }
}

// ---------------------------------------------------------------------------
// Out-projection GEMM: m97-structure 128x128 kernel (512 blocks =
// 2 balanced rounds on 256 CUs).
// ---------------------------------------------------------------------------
__global__ __launch_bounds__(256) void gemm_bt_kernel(
    const u16* __restrict__ X, const u16* __restrict__ W,
    float* __restrict__ C, int M, int N, int K)
{
    __shared__ __align__(16) u16 As[128 * 64];
    __shared__ __align__(16) u16 Bs[128 * 64];

    const int tid  = threadIdx.x;
    const int wave = tid >> 6;
    const int lane = tid & 63;
    const int lq = lane >> 4;      // quad 0..3
    const int lm = lane & 15;
    const int m0 = blockIdx.x * 128;
    const int n0 = blockIdx.y * 128;
    const int wm = (wave & 1) * 64;
    const int wn = (wave >> 1) * 64;

    f32x4 acc[4][4] = {};

    const int r0 = wave * 32 + (lane >> 3);
    const int c0 = (lane & 7) * 8;
    const u16* gA = X + (size_t)(m0 + r0) * K + c0;
    const u16* gB = W + (size_t)(n0 + r0) * K + c0;
    u16* lA = As + wave * 32 * 64;   // wave-uniform base
    u16* lB = Bs + wave * 32 * 64;

    for (int k0 = 0; k0 < K; k0 += 64) {
#pragma unroll
        for (int p = 0; p < 4; ++p) {
            gl2lds16(gA + (size_t)p * 8 * K + k0, lA + p * 8 * 64);
            gl2lds16(gB + (size_t)p * 8 * K + k0, lB + p * 8 * 64);
        }
        __syncthreads();
#pragma unroll
        for (int ks = 0; ks < 2; ++ks) {
            bf16x8 af[4], bfr[4];
#pragma unroll
            for (int t = 0; t < 4; ++t)
                af[t] = *(const bf16x8*)(As + (wm + t * 16 + lm) * 64 + ks * 32 + lq * 8);
#pragma unroll
            for (int t = 0; t < 4; ++t)
                bfr[t] = *(const bf16x8*)(Bs + (wn + t * 16 + lm) * 64 + ks * 32 + lq * 8);
#pragma unroll
            for (int i = 0; i < 4; ++i)
#pragma unroll
                for (int j = 0; j < 4; ++j)
                    acc[i][j] = __builtin_amdgcn_mfma_f32_16x16x32_bf16(
                        af[i], bfr[j], acc[i][j], 0, 0, 0);
        }
        __syncthreads();
    }

#pragma unroll
    for (int i = 0; i < 4; ++i)
#pragma unroll
        for (int j = 0; j < 4; ++j) {
            int rowb = m0 + wm + i * 16 + lq * 4;
            int col  = n0 + wn + j * 16 + lm;
#pragma unroll
            for (int r = 0; r < 4; ++r)
                C[(size_t)(rowb + r) * N + col] = acc[i][j][r];
        }
}

// ---------------------------------------------------------------------------
// Flash causal attention, qf=4 (64 queries/wave), SPLIT-K over 2 waves.
// ROUND-5 RESTRUCTURE: flattened chunk stream + SOFTWARE PIPELINE.
// Round-4 taught: occupancy is NOT binding (grid 2x, LDS /2.7 -> 0% change);
// waves are ~93% stalled on per-chunk serial latency (VALUBusy 29% matches
// static VALU count). The old `#pragma unroll` c-loop with `if(c<=ksmax)`
// guards + aliasing LDS P-writes blocked cross-chunk load hoisting, so every
// chunk opened with a full L2-latency K-load wait.
// Now: K for chunk i+1 prefetched into ping-pong register sets (kA/kB,
// static indexing via 2-unrolled loop; per-wave chunk count is always even),
// V loads issued at chunk start BEFORE the K-prefetch (PV's wait is then
// vmcnt(4), leaving next-K in flight; V latency hides under QK+softmax).
// LDS P-staging and split-K combine kept verbatim from round 4.
// ---------------------------------------------------------------------------
__global__ __launch_bounds__(128) void attn_kernel(
    const u16* __restrict__ Qg, const u16* __restrict__ Kg,
    const u16* __restrict__ Vtg, u16* __restrict__ Og)
{
    __shared__ __align__(16) u16 Pl[2 * 64 * 40];    // 10.25KB; reused for combine

    const int tid  = threadIdx.x;
    const int wave = tid >> 6;
    const int lane = tid & 63;
    const int lq = lane >> 4, lm = lane & 15;
    const int id = blockIdx.x;            // 0..2047
    const int xs = id & 7;                // XCD slot
    const int bh = xs + 8 * ((id >> 3) & 7);   // 8 bh per XCD slot
    const int qj = 31 - (id >> 6);        // longest-first dispatch order
    const int b = bh >> 4, h = bh & 15;

    const size_t batchoff = (size_t)b * T_ * D_;
    const size_t headoff  = (size_t)h * DH_;
    const size_t vbase    = (size_t)bh * DH_ * T_;

    u16* pw = Pl + wave * 64 * 40;

    const int qw  = qj * 64;
    const int ktd = qj >> 1;               // diagonal 128-key tile
    const int odd = qj & 1;                // which half of diag tile
    const int cmax_d = odd ? 3 : 1;        // 32-key chunks in diag ktile - 1

    // Q fragments (B-operand): lane holds query qw+qf*16+lm, dh=ks*32+lq*8+j
    bf16x8 aq[4][2];
#pragma unroll
    for (int qf = 0; qf < 4; ++qf) {
        const u16* qrow = Qg + batchoff + (size_t)(qw + qf * 16 + lm) * D_ + headoff;
        aq[qf][0] = *(const bf16x8*)(qrow + lq * 8);
        aq[qf][1] = *(const bf16x8*)(qrow + 32 + lq * 8);
    }

    f32x4 oaccT[4][4] = {};          // [qf][dh-frag]; row=dh, col=query
    float l_lane[4] = {0.f, 0.f, 0.f, 0.f};

    // per-lane base pointers (lm-row, lq-chunk folded in)
    const u16* Kb_lane = Kg + batchoff + headoff + (size_t)lm * D_ + lq * 8;
    const u16* Vb_lane = Vtg + vbase + (size_t)lm * T_ + lq * 8;

    // chunk count for this wave's split-K parity (always EVEN: full ktile=4,
    // diag ktile = 2 or 4)
    int total = 0;
    for (int k = wave; k <= ktd; k += 2)
        total += (k == ktd) ? (cmax_d + 1) : 4;

    int kt = wave, c = 0;
    bf16x8 kA[4], kB[4];
    // prologue: prefetch first chunk's K (kt<=1 -> always in-bounds)
    {
        const u16* kr0 = Kb_lane + ((size_t)(kt * 128) << 10);   // *D_
        kA[0] = *(const bf16x8*)(kr0);
        kA[1] = *(const bf16x8*)(kr0 + 32);
        kA[2] = *(const bf16x8*)(kr0 + 16 * D_);
        kA[3] = *(const bf16x8*)(kr0 + 16 * D_ + 32);
    }

    auto body = [&](bf16x8 (&kc)[4], bf16x8 (&kn)[4])
        __attribute__((always_inline)) -> void {
        const int ckt = kt, cc = c;
        int nkt = ckt, nc = cc + 1;
        const int cmax = (ckt == ktd) ? cmax_d : 3;
        if (nc > cmax) { nkt = ckt + 2; nc = 0; }
        const int kb = ckt * 128 + cc * 32;      // first key of this chunk

        // ---- current-chunk V loads FIRST (PV waits vmcnt(4): next-K stays
        //      in flight; V latency hides under QK+softmax) ----
        bf16x8 vf[4];
#pragma unroll
        for (int mo = 0; mo < 4; ++mo)
            vf[mo] = *(const bf16x8*)(Vb_lane + (size_t)mo * 16 * T_ + kb);

        // ---- next-chunk K prefetch (wave-uniform guard: OOB past diag) ----
        if (nkt <= ktd) {
            const u16* kr0 = Kb_lane + ((size_t)(nkt * 128 + nc * 32) << 10);
            kn[0] = *(const bf16x8*)(kr0);
            kn[1] = *(const bf16x8*)(kr0 + 32);
            kn[2] = *(const bf16x8*)(kr0 + 16 * D_);
            kn[3] = *(const bf16x8*)(kr0 + 16 * D_ + 32);
        }

        // ---- QK (K in regs) -> mask -> exp2 -> pack -> LDS ----
#pragma unroll
        for (int qf = 0; qf < 4; ++qf) {
            f32x4 s0 = {0.f, 0.f, 0.f, 0.f}, s1 = {0.f, 0.f, 0.f, 0.f};
            s0 = __builtin_amdgcn_mfma_f32_16x16x32_bf16(kc[0], aq[qf][0], s0, 0, 0, 0);
            s0 = __builtin_amdgcn_mfma_f32_16x16x32_bf16(kc[1], aq[qf][1], s0, 0, 0, 0);
            s1 = __builtin_amdgcn_mfma_f32_16x16x32_bf16(kc[2], aq[qf][0], s1, 0, 0, 0);
            s1 = __builtin_amdgcn_mfma_f32_16x16x32_bf16(kc[3], aq[qf][1], s1, 0, 0, 0);
            if (ckt == ktd) {                    // diag ktile: causal mask
                int query = qw + qf * 16 + lm;
                int kb0 = kb + lq * 4;
#pragma unroll
                for (int r = 0; r < 4; ++r) {
                    if (kb0 + r > query)      s0[r] = -1e9f;
                    if (kb0 + 16 + r > query) s1[r] = -1e9f;
                }
            }
            float p00 = __builtin_amdgcn_exp2f(s0[0]);
            float p01 = __builtin_amdgcn_exp2f(s0[1]);
            float p02 = __builtin_amdgcn_exp2f(s0[2]);
            float p03 = __builtin_amdgcn_exp2f(s0[3]);
            float p10 = __builtin_amdgcn_exp2f(s1[0]);
            float p11 = __builtin_amdgcn_exp2f(s1[1]);
            float p12 = __builtin_amdgcn_exp2f(s1[2]);
            float p13 = __builtin_amdgcn_exp2f(s1[3]);
            l_lane[qf] += ((p00 + p01) + (p02 + p03)) + ((p10 + p11) + (p12 + p13));
            uint2 d0, d1;
            d0.x = pack2(p00, p01); d0.y = pack2(p02, p03);
            d1.x = pack2(p10, p11); d1.y = pack2(p12, p13);
            *(uint2*)(pw + (qf * 16 + lm) * 40 + lq * 4)      = d0;
            *(uint2*)(pw + (qf * 16 + lm) * 40 + 16 + lq * 4) = d1;
        }

        // ---- O^T += V^T P^T ----
        bf16x8 pf[4];
#pragma unroll
        for (int qf = 0; qf < 4; ++qf)
            pf[qf] = *(const bf16x8*)(pw + (qf * 16 + lm) * 40 + lq * 8);
#pragma unroll
        for (int mo = 0; mo < 4; ++mo)
#pragma unroll
            for (int qf = 0; qf < 4; ++qf)
                oaccT[qf][mo] = __builtin_amdgcn_mfma_f32_16x16x32_bf16(
                    vf[mo], pf[qf], oaccT[qf][mo], 0, 0, 0);

        kt = nkt; c = nc;
    };

#pragma unroll 1
    for (int it = 0; it < total; it += 2) {
        body(kA, kB);
        body(kB, kA);
    }

    // ---- split-K combine through retired Pl (two 8-slot rounds) ----
    // slot s=(qf&1)*4+mo, lane slot-index XOR-transposed: conflict-free.
    float* Cf = (float*)Pl;                      // 2560 floats
    const int cswz = (lane ^ (lane >> 3)) * 4;   // f32x4 float-offset in slot
    __syncthreads();                             // both waves done with Pl
    if (wave == 1) {
#pragma unroll
        for (int qf = 0; qf < 2; ++qf)
#pragma unroll
            for (int mo = 0; mo < 4; ++mo)
                *(f32x4*)&Cf[(qf * 4 + mo) * 256 + cswz] = oaccT[qf][mo];
#pragma unroll
        for (int qf = 0; qf < 4; ++qf)
            Cf[2048 + qf * 64 + lane] = l_lane[qf];   // l partials (1KB tail)
    }
    __syncthreads();
    if (wave == 0) {
#pragma unroll
        for (int qf = 0; qf < 2; ++qf)
#pragma unroll
            for (int mo = 0; mo < 4; ++mo) {
                f32x4 o = *(const f32x4*)&Cf[(qf * 4 + mo) * 256 + cswz];
#pragma unroll
                for (int r = 0; r < 4; ++r) oaccT[qf][mo][r] += o[r];
            }
#pragma unroll
        for (int qf = 0; qf < 4; ++qf) l_lane[qf] += Cf[2048 + qf * 64 + lane];
    }
    __syncthreads();
    if (wave == 1) {
#pragma unroll
        for (int qf = 2; qf < 4; ++qf)
#pragma unroll
            for (int mo = 0; mo < 4; ++mo)
                *(f32x4*)&Cf[((qf - 2) * 4 + mo) * 256 + cswz] = oaccT[qf][mo];
    }
    __syncthreads();
    if (wave == 0) {
#pragma unroll
        for (int qf = 2; qf < 4; ++qf)
#pragma unroll
            for (int mo = 0; mo < 4; ++mo) {
                f32x4 o = *(const f32x4*)&Cf[((qf - 2) * 4 + mo) * 256 + cswz];
#pragma unroll
                for (int r = 0; r < 4; ++r) oaccT[qf][mo][r] += o[r];
            }
        // epilogue: reduce l across quads, O = O^T / l, packed stores
#pragma unroll
        for (int qf = 0; qf < 4; ++qf) {
            float l = l_lane[qf];
            l += __shfl_xor(l, 16, 64);
            l += __shfl_xor(l, 32, 64);
            float inv = 1.0f / l;
            int row = qw + qf * 16 + lm;
            u16* obase = Og + batchoff + (size_t)row * D_ + headoff;
#pragma unroll
            for (int mo = 0; mo < 4; ++mo) {
                uint2 d;
                d.x = pack2(oaccT[qf][mo][0] * inv, oaccT[qf][mo][1] * inv);
                d.y = pack2(oaccT[qf][mo][2] * inv, oaccT[qf][mo][3] * inv);
                *(uint2*)(obase + mo * 16 + lq * 4) = d;
            }
        }
    }
}

// ---------------------------------------------------------------------------
extern "C" void kernel_launch(void* const* d_in, const int* in_sizes, int n_in,
                              void* d_out, int out_size, void* d_ws, size_t ws_size,
                              hipStream_t stream)
{
    const float* x  = (const float*)d_in[0];   // fp32 (B,T,D)
    // d_in[1] = mask (int32 tril) — causality hardcoded, not read
    const float* Wq = (const float*)d_in[2];   // fp32 (D,D)
    const float* Wk = (const float*)d_in[3];
    const float* Wv = (const float*)d_in[4];
    const float* Wo = (const float*)d_in[5];

    const size_t DD = (size_t)D_ * D_;
    u16* Qb  = (u16*)d_ws;        // Q (scaled), K, V(trans) contiguous
    u16* Kb  = Qb + NT_;
    u16* Vb  = Kb + NT_;
    u16* Ob  = Vb + NT_;
    u16* xb  = Ob + NT_;
    u16* wb  = xb + NT_;          // 4 x DD: Wq, Wk, Wv, Wo

    const int M = B_ * T_;        // 8192

    cvt_x_kernel<<<dim3((int)(NT_ / 8 / 256)), 256, 0, stream>>>(x, xb, (int)(NT_ / 8));
    cvt_w_kernel<<<dim3((int)(DD / 8 / 256), 4), 256, 0, stream>>>(Wq, Wk, Wv, Wo, wb);

    // fused Q/K/V projection: x @ [Wq;Wk;Wv]^T, N=3072, routed epilogue
    // 256x192 tile, 8 waves, read-pipelined: grid = 32*16 = 512 blocks (2 full rounds)
    gemm8_kernel<3><<<dim3((M / 256) * (3 * D_ / 192)), 512, 0, stream>>>(
        xb, wb, Qb, M, 3 * D_, D_);

    // split-K (2 waves/block) attention: 2048 blocks x 128 thr (1 q-tile each),
    // K-prefetch software pipeline, longest-first, XCD-swizzled
    attn_kernel<<<dim3(2048), 128, 0, stream>>>(Qb, Kb, Vb, Ob);

    // output projection -> fp32: 128^2 tile, 512 blocks (2 balanced rounds)
    gemm_bt_kernel<<<dim3(M / 128, D_ / 128), 256, 0, stream>>>(
        Ob, wb + 3 * DD, (float*)d_out, M, D_, D_);
}

// Round 6
// 269.333 us; speedup vs baseline: 1.0260x; 1.0260x over previous
//
#include <hip/hip_runtime.h>
#include <stdint.h>

// Problem constants: B=4, T=2048, D=1024, H=16, DH=64
#define B_  4
#define T_  2048
#define D_  1024
#define H_  16
#define DH_ 64

typedef unsigned short u16;
typedef __attribute__((ext_vector_type(8))) short bf16x8;   // 8 bf16 = 4 VGPRs
typedef __attribute__((ext_vector_type(8))) unsigned short u16x8;
typedef __attribute__((ext_vector_type(4))) unsigned short u16x4;
typedef __attribute__((ext_vector_type(4))) float f32x4;

#define NT_ ((size_t)B_ * T_ * D_)          // 8.4M elements
#define QSCALE 0.18033688011112043f         // log2(e)/sqrt(DH): exp2-domain softmax

__device__ __forceinline__ u16 f2bf(float f) {
    union { float f; uint32_t u; } v; v.f = f;
    uint32_t r = v.u + 0x7FFFu + ((v.u >> 16) & 1u);   // RNE
    return (u16)(r >> 16);
}

// pack two fp32 into one dword of 2 bf16 (truncation) — single v_perm_b32
__device__ __forceinline__ uint32_t pack2(float lo, float hi) {
    union { float f; uint32_t u; } a, b; a.f = lo; b.f = hi;
    return __builtin_amdgcn_perm(b.u, a.u, 0x07060302u);
}

// async 16B global->LDS (lds dest is wave-uniform; HW adds lane*16)
__device__ __forceinline__ void gl2lds16(const u16* g, u16* l) {
    __builtin_amdgcn_global_load_lds(
        (const __attribute__((address_space(1))) unsigned int*)g,
        (__attribute__((address_space(3))) unsigned int*)l,
        16, 0, 0);
}

#define VMCNT(n) asm volatile("s_waitcnt vmcnt(" #n ")" ::: "memory")
#define SB0()    __builtin_amdgcn_sched_barrier(0)

// swizzled LDS fragment read: row in element-rows (128B stride), ks selects
// 32-elem K-half, lq*16B within; swzr = (lm&7)<<4 XOR (matches staging layout)
__device__ __forceinline__ bf16x8 ldsrd(const u16* base, int row, int ks,
                                        int lq, int swzr) {
    int off = row * 128 + ks * 64 + lq * 16;   // bytes
    return *(const bf16x8*)((const char*)base + (off ^ swzr));
}

// ---------------------------------------------------------------------------
// fp32 -> bf16 converters
// ---------------------------------------------------------------------------
__global__ __launch_bounds__(256) void cvt_x_kernel(
    const float* __restrict__ src, u16* __restrict__ dst, int n8)
{
    int i = blockIdx.x * 256 + threadIdx.x;
    if (i >= n8) return;
    f32x4 a = ((const f32x4*)src)[2 * i];
    f32x4 b = ((const f32x4*)src)[2 * i + 1];
    u16x8 o;
    o[0]=f2bf(a[0]); o[1]=f2bf(a[1]); o[2]=f2bf(a[2]); o[3]=f2bf(a[3]);
    o[4]=f2bf(b[0]); o[5]=f2bf(b[1]); o[6]=f2bf(b[2]); o[7]=f2bf(b[3]);
    ((u16x8*)dst)[i] = o;
}

__global__ __launch_bounds__(256) void cvt_w_kernel(
    const float* __restrict__ w0, const float* __restrict__ w1,
    const float* __restrict__ w2, const float* __restrict__ w3,
    u16* __restrict__ dst)   // 4 consecutive D*D segments: Wq,Wk,Wv,Wo
{
    const float* src = (blockIdx.y == 0) ? w0 : (blockIdx.y == 1) ? w1
                     : (blockIdx.y == 2) ? w2 : w3;
    u16* d = dst + (size_t)blockIdx.y * (D_ * D_);
    int i = blockIdx.x * 256 + threadIdx.x;
    f32x4 a = ((const f32x4*)src)[2 * i];
    f32x4 b = ((const f32x4*)src)[2 * i + 1];
    u16x8 o;
    o[0]=f2bf(a[0]); o[1]=f2bf(a[1]); o[2]=f2bf(a[2]); o[3]=f2bf(a[3]);
    o[4]=f2bf(b[0]); o[5]=f2bf(b[1]); o[6]=f2bf(b[2]); o[7]=f2bf(b[3]);
    ((u16x8*)d)[i] = o;
}

// ---------------------------------------------------------------------------
// QKV GEMM: 256x192 tile, 8 waves, read-pipelined 4-phase schedule
// (unchanged from round 3 — verified working)
// ---------------------------------------------------------------------------
template<int OUT_MODE>
__global__ __launch_bounds__(512) void gemm8_kernel(
    const u16* __restrict__ X, const u16* __restrict__ W,
    void* __restrict__ C, int M, int N, int K)
{
    __shared__ __align__(16) u16 Ab2[2][256 * 64];   // 64 KB
    __shared__ __align__(16) u16 Bb2[2][192 * 64];   // 48 KB

    const int tid  = threadIdx.x;
    const int wave = tid >> 6;
    const int lane = tid & 63;
    const int lq = lane >> 4, lm = lane & 15;
    const int wm = wave >> 2;      // wave's M slot (0..1) -> 128 rows
    const int wn = wave & 3;       // wave's N slot (0..3) -> 48 cols

    // rect XCD swizzle: XCD (bid&7) owns an 8x8 tile rectangle
    const int xcd = (int)blockIdx.x & 7;
    const int idx = (int)blockIdx.x >> 3;   // 0..63
    const int m0 = (((xcd & 3) << 3) + (idx & 7)) << 8;      // 32 M-tiles
    const int n0 = (((xcd >> 2) << 3) + (idx >> 3)) * 192;   // 16 N-tiles

    // staging: each gl2lds covers 64 rows (512thr x 16B = 8KB); 16B chunk
    // scol pre-swizzled so LINEAR LDS DMA writes land in swizzled layout.
    const int srow = wave * 8 + (lane >> 3);                 // 0..63
    const int scol = ((lane & 7) ^ (lane >> 3)) << 3;        // elements
    const u16* gA = X + (size_t)(m0 + srow) * K + scol;
    const u16* gB = W + (size_t)(n0 + srow) * K + scol;
    const size_t rK64 = (size_t)64 * K;

    const int swzr = (lm & 7) << 4;        // ds_read byte-address XOR

    f32x4 acc[8][3] = {};                  // 96 AGPR
    bf16x8 afA[2][2], afB[2][2];           // A frags, ping-pong by phase parity
    bf16x8 bqA[3][2], bqB[3][2];           // B frags, ping-pong by tile parity
    const int NT = K >> 6;                 // 16

    // ---- prologue: stage A0(4), B0(3), B1(3) ----
    gl2lds16(gA,            (u16*)Ab2[0] + wave * 512);
    gl2lds16(gA + rK64,     (u16*)Ab2[0] + 4096  + wave * 512);
    gl2lds16(gA + 2 * rK64, (u16*)Ab2[0] + 8192  + wave * 512);
    gl2lds16(gA + 3 * rK64, (u16*)Ab2[0] + 12288 + wave * 512);
    gl2lds16(gB,            (u16*)Bb2[0] + wave * 512);
    gl2lds16(gB + rK64,     (u16*)Bb2[0] + 4096  + wave * 512);
    gl2lds16(gB + 2 * rK64, (u16*)Bb2[0] + 8192  + wave * 512);
    gl2lds16(gB + 64,            (u16*)Bb2[1] + wave * 512);
    gl2lds16(gB + 64 + rK64,     (u16*)Bb2[1] + 4096  + wave * 512);
    gl2lds16(gB + 64 + 2 * rK64, (u16*)Bb2[1] + 8192  + wave * 512);
    VMCNT(3);                               // A0,B0 landed; B1 (3) in flight
    __builtin_amdgcn_s_barrier();
    // initial frags: tile0 phase0 A + tile0 B
#pragma unroll
    for (int i2 = 0; i2 < 2; ++i2)
#pragma unroll
        for (int ks = 0; ks < 2; ++ks)
            afA[i2][ks] = ldsrd(Ab2[0], wm * 128 + i2 * 16 + lm, ks, lq, swzr);
#pragma unroll
    for (int j = 0; j < 3; ++j)
#pragma unroll
        for (int ks = 0; ks < 2; ++ks)
            bqA[j][ks] = ldsrd(Bb2[0], wn * 48 + j * 16 + lm, ks, lq, swzr);

    // one K-tile; af sets toggle per phase (q0:A, q1:B, q2:A, q3:B), bq sets
    // toggle per tile (all register indices static after inlining).
    auto tile_body = [&](int t, bf16x8 (&bqU)[3][2], bf16x8 (&bqF)[3][2])
        __attribute__((always_inline)) -> void {
        const u16* Ac = Ab2[t & 1];
        const u16* An = Ab2[(t + 1) & 1];
        const u16* Bn = Bb2[(t + 1) & 1];
        u16* Abn = (u16*)Ab2[(t + 1) & 1];
        u16* Bbc = (u16*)Bb2[t & 1];
        const bool stA = (t + 1 < NT);
        const bool stB = (t + 2 < NT);
        const u16* gAs = gA + (size_t)(t + 1) * 64;
        const u16* gBs = gB + (size_t)(t + 2) * 64;

#define MFMA_PH(Q, AF, BQ)                                                  \
        __builtin_amdgcn_s_setprio(1);                                      \
        _Pragma("unroll")                                                   \
        for (int ks = 0; ks < 2; ++ks)                                      \
            _Pragma("unroll")                                               \
            for (int i2 = 0; i2 < 2; ++i2)                                  \
                _Pragma("unroll")                                           \
                for (int j = 0; j < 3; ++j)                                 \
                    acc[2 * (Q) + i2][j] =                                  \
                        __builtin_amdgcn_mfma_f32_16x16x32_bf16(            \
                            AF[i2][ks], BQ[j][ks], acc[2 * (Q) + i2][j],    \
                            0, 0, 0);                                       \
        __builtin_amdgcn_s_setprio(0);

#define RD_AF(SET, P, BASE)                                                 \
        _Pragma("unroll")                                                   \
        for (int i2 = 0; i2 < 2; ++i2)                                      \
            _Pragma("unroll")                                               \
            for (int ks = 0; ks < 2; ++ks)                                  \
                SET[i2][ks] = ldsrd(BASE,                                   \
                    wm * 128 + (2 * (P) + i2) * 16 + lm, ks, lq, swzr);

        // ---- phase 0: uses afA; read afB(p1); stage A[t+1] h0 ----
        RD_AF(afB, 1, Ac);
        if (stA) {
            gl2lds16(gAs,        Abn + wave * 512);
            gl2lds16(gAs + rK64, Abn + 4096 + wave * 512);
        }
        SB0(); __builtin_amdgcn_s_barrier(); SB0();
        MFMA_PH(0, afA, bqU); SB0();
        __builtin_amdgcn_s_barrier();

        // ---- phase 1: uses afB; read afA(p2); stage A[t+1] h1 ----
        RD_AF(afA, 2, Ac);
        if (stA) {
            gl2lds16(gAs + 2 * rK64, Abn + 8192  + wave * 512);
            gl2lds16(gAs + 3 * rK64, Abn + 12288 + wave * 512);
        }
        SB0(); __builtin_amdgcn_s_barrier(); SB0();
        MFMA_PH(1, afB, bqU); SB0();
        __builtin_amdgcn_s_barrier();

        // ---- phase 2: uses afA; read afB(p3); stage B[t+2] c0,c1 ----
        RD_AF(afB, 3, Ac);
        if (stB) {
            gl2lds16(gBs,        Bbc + wave * 512);
            gl2lds16(gBs + rK64, Bbc + 4096 + wave * 512);
        }
        SB0(); __builtin_amdgcn_s_barrier(); SB0();
        MFMA_PH(2, afA, bqU); SB0();
        if (stB)      { VMCNT(2); }   // A[t+1],B[t+1] landed; B[t+2]h0 in flight
        else if (stA) { VMCNT(0); }   // t==NT-2: drain A[NT-1]
        __builtin_amdgcn_s_barrier();

        // ---- phase 3: uses afB; read next-tile afA(p0)+bqF; stage B[t+2] c2 ----
        if (stA) {
            RD_AF(afA, 0, An);
#pragma unroll
            for (int j = 0; j < 3; ++j)
#pragma unroll
                for (int ks = 0; ks < 2; ++ks)
                    bqF[j][ks] = ldsrd(Bn, wn * 48 + j * 16 + lm, ks, lq, swzr);
        }
        if (stB)
            gl2lds16(gBs + 2 * rK64, Bbc + 8192 + wave * 512);
        SB0(); __builtin_amdgcn_s_barrier(); SB0();
        MFMA_PH(3, afB, bqU); SB0();
        __builtin_amdgcn_s_barrier();
#undef RD_AF
#undef MFMA_PH
    };

#pragma unroll 1
    for (int tt = 0; tt < NT; tt += 2) {
        tile_body(tt,     bqA, bqB);
        tile_body(tt + 1, bqB, bqA);
    }

    // ---- epilogue: acc[i][j][r] -> row m0+wm*128+i*16+lq*4+r,
    //                               col n0+wn*48+j*16+lm ----
#pragma unroll
    for (int i = 0; i < 8; ++i)
#pragma unroll
        for (int j = 0; j < 3; ++j) {
            int rowb = m0 + wm * 128 + i * 16 + lq * 4;
            int col  = n0 + wn * 48 + j * 16 + lm;
            if (OUT_MODE == 2) {
#pragma unroll
                for (int r = 0; r < 4; ++r)
                    ((float*)C)[(size_t)(rowb + r) * N + col] = acc[i][j][r];
            } else {
                u16* Qp = (u16*)C;
                int region = col >> 10;      // per-fragment: 192 tile straddles
                int colr = col & 1023;
                if (region == 0) {
#pragma unroll
                    for (int r = 0; r < 4; ++r)
                        Qp[(size_t)(rowb + r) * D_ + colr] = f2bf(acc[i][j][r] * QSCALE);
                } else if (region == 1) {
#pragma unroll
                    for (int r = 0; r < 4; ++r)
                        (Qp + NT_)[(size_t)(rowb + r) * D_ + colr] = f2bf(acc[i][j][r]);
                } else {
                    int b = rowb >> 11, tt2 = rowb & (T_ - 1);   // 4 consecutive t
                    u16x4 pk;
#pragma unroll
                    for (int r = 0; r < 4; ++r) pk[r] = f2bf(acc[i][j][r]);
                    *(u16x4*)((Qp + 2 * NT_) + ((size_t)b * D_ + colr) * T_ + tt2) = pk;
                }
            }
        }
}

// ---------------------------------------------------------------------------
// Out-projection GEMM: 256x128 tile, 8 waves (2M x 4N: 32 cols/wave),
// SAME read-pipelined 4-phase schedule as gemm8_kernel, B-side narrowed to
// 2 fragments. Grid = 32 x 8 = 256 blocks = EXACTLY one block per CU (one
// full round; old 128^2 kernel ran 512 blocks in 2 uneven rounds at ~550TF).
// LDS: A 64KB + B 32KB = 96KB (1 block/CU). acc[8][2] = 64 AGPR.
// Stages: q0/q1 = A[t+1] (2+2), q2/q3 = B[t+2] (1+1); VMCNT(1) at q2-end
// (oldest 5 = B[t+1]h1 + A[t+1] drained; B[t+2]h0 stays in flight).
// ---------------------------------------------------------------------------
__global__ __launch_bounds__(512) void gemm8o_kernel(
    const u16* __restrict__ X, const u16* __restrict__ W,
    float* __restrict__ C)    // M=8192, N=1024, K=1024
{
    __shared__ __align__(16) u16 Ab2[2][256 * 64];   // 64 KB
    __shared__ __align__(16) u16 Bb2[2][128 * 64];   // 32 KB

    const int K = 1024, N = 1024;
    const int tid  = threadIdx.x;
    const int wave = tid >> 6;
    const int lane = tid & 63;
    const int lq = lane >> 4, lm = lane & 15;
    const int wm = wave >> 2;      // 0..1 -> 128 rows
    const int wn = wave & 3;       // 0..3 -> 32 cols

    // rect XCD swizzle: XCD owns an 8x4 tile rectangle (32 M-tiles, 8 N-tiles)
    const int xcd = (int)blockIdx.x & 7;
    const int idx = (int)blockIdx.x >> 3;   // 0..31
    const int m0 = (((xcd & 3) << 3) + (idx & 7)) << 8;
    const int n0 = (((xcd >> 2) << 2) + (idx >> 3)) << 7;

    const int srow = wave * 8 + (lane >> 3);                 // 0..63
    const int scol = ((lane & 7) ^ (lane >> 3)) << 3;        // elements
    const u16* gA = X + (size_t)(m0 + srow) * K + scol;
    const u16* gB = W + (size_t)(n0 + srow) * K + scol;
    const size_t rK64 = (size_t)64 * K;

    const int swzr = (lm & 7) << 4;

    f32x4 acc[8][2] = {};                  // 64 AGPR
    bf16x8 afA[2][2], afB[2][2];
    bf16x8 bqA[2][2], bqB[2][2];
    const int NT = 16;

    // ---- prologue: stage A0(4), B0(2), B1(2) ----
    gl2lds16(gA,            (u16*)Ab2[0] + wave * 512);
    gl2lds16(gA + rK64,     (u16*)Ab2[0] + 4096  + wave * 512);
    gl2lds16(gA + 2 * rK64, (u16*)Ab2[0] + 8192  + wave * 512);
    gl2lds16(gA + 3 * rK64, (u16*)Ab2[0] + 12288 + wave * 512);
    gl2lds16(gB,            (u16*)Bb2[0] + wave * 512);
    gl2lds16(gB + rK64,     (u16*)Bb2[0] + 4096  + wave * 512);
    gl2lds16(gB + 64,            (u16*)Bb2[1] + wave * 512);
    gl2lds16(gB + 64 + rK64,     (u16*)Bb2[1] + 4096  + wave * 512);
    VMCNT(2);                               // A0,B0 landed; B1 (2) in flight
    __builtin_amdgcn_s_barrier();
#pragma unroll
    for (int i2 = 0; i2 < 2; ++i2)
#pragma unroll
        for (int ks = 0; ks < 2; ++ks)
            afA[i2][ks] = ldsrd(Ab2[0], wm * 128 + i2 * 16 + lm, ks, lq, swzr);
#pragma unroll
    for (int j = 0; j < 2; ++j)
#pragma unroll
        for (int ks = 0; ks < 2; ++ks)
            bqA[j][ks] = ldsrd(Bb2[0], wn * 32 + j * 16 + lm, ks, lq, swzr);

    auto tile_body = [&](int t, bf16x8 (&bqU)[2][2], bf16x8 (&bqF)[2][2])
        __attribute__((always_inline)) -> void {
        const u16* Ac = Ab2[t & 1];
        const u16* An = Ab2[(t + 1) & 1];
        const u16* Bn = Bb2[(t + 1) & 1];
        u16* Abn = (u16*)Ab2[(t + 1) & 1];
        u16* Bbc = (u16*)Bb2[t & 1];
        const bool stA = (t + 1 < NT);
        const bool stB = (t + 2 < NT);
        const u16* gAs = gA + (size_t)(t + 1) * 64;
        const u16* gBs = gB + (size_t)(t + 2) * 64;

#define MFMA_PHO(Q, AF, BQ)                                                 \
        __builtin_amdgcn_s_setprio(1);                                      \
        _Pragma("unroll")                                                   \
        for (int ks = 0; ks < 2; ++ks)                                      \
            _Pragma("unroll")                                               \
            for (int i2 = 0; i2 < 2; ++i2)                                  \
                _Pragma("unroll")                                           \
                for (int j = 0; j < 2; ++j)                                 \
                    acc[2 * (Q) + i2][j] =                                  \
                        __builtin_amdgcn_mfma_f32_16x16x32_bf16(            \
                            AF[i2][ks], BQ[j][ks], acc[2 * (Q) + i2][j],    \
                            0, 0, 0);                                       \
        __builtin_amdgcn_s_setprio(0);

#define RD_AFO(SET, P, BASE)                                                \
        _Pragma("unroll")                                                   \
        for (int i2 = 0; i2 < 2; ++i2)                                      \
            _Pragma("unroll")                                               \
            for (int ks = 0; ks < 2; ++ks)                                  \
                SET[i2][ks] = ldsrd(BASE,                                   \
                    wm * 128 + (2 * (P) + i2) * 16 + lm, ks, lq, swzr);

        // ---- phase 0 ----
        RD_AFO(afB, 1, Ac);
        if (stA) {
            gl2lds16(gAs,        Abn + wave * 512);
            gl2lds16(gAs + rK64, Abn + 4096 + wave * 512);
        }
        SB0(); __builtin_amdgcn_s_barrier(); SB0();
        MFMA_PHO(0, afA, bqU); SB0();
        __builtin_amdgcn_s_barrier();

        // ---- phase 1 ----
        RD_AFO(afA, 2, Ac);
        if (stA) {
            gl2lds16(gAs + 2 * rK64, Abn + 8192  + wave * 512);
            gl2lds16(gAs + 3 * rK64, Abn + 12288 + wave * 512);
        }
        SB0(); __builtin_amdgcn_s_barrier(); SB0();
        MFMA_PHO(1, afB, bqU); SB0();
        __builtin_amdgcn_s_barrier();

        // ---- phase 2 ----
        RD_AFO(afB, 3, Ac);
        if (stB)
            gl2lds16(gBs, Bbc + wave * 512);
        SB0(); __builtin_amdgcn_s_barrier(); SB0();
        MFMA_PHO(2, afA, bqU); SB0();
        if (stB)      { VMCNT(1); }   // B[t+1]+A[t+1] landed; B[t+2]h0 in flight
        else if (stA) { VMCNT(0); }   // t==NT-2: drain A[NT-1] (+B tail)
        __builtin_amdgcn_s_barrier();

        // ---- phase 3 ----
        if (stA) {
            RD_AFO(afA, 0, An);
#pragma unroll
            for (int j = 0; j < 2; ++j)
#pragma unroll
                for (int ks = 0; ks < 2; ++ks)
                    bqF[j][ks] = ldsrd(Bn, wn * 32 + j * 16 + lm, ks, lq, swzr);
        }
        if (stB)
            gl2lds16(gBs + rK64, Bbc + 4096 + wave * 512);
        SB0(); __builtin_amdgcn_s_barrier(); SB0();
        MFMA_PHO(3, afB, bqU); SB0();
        __builtin_amdgcn_s_barrier();
#undef RD_AFO
#undef MFMA_PHO
    };

#pragma unroll 1
    for (int tt = 0; tt < NT; tt += 2) {
        tile_body(tt,     bqA, bqB);
        tile_body(tt + 1, bqB, bqA);
    }

    // ---- epilogue: fp32 natural ----
#pragma unroll
    for (int i = 0; i < 8; ++i)
#pragma unroll
        for (int j = 0; j < 2; ++j) {
            int rowb = m0 + wm * 128 + i * 16 + lq * 4;
            int col  = n0 + wn * 32 + j * 16 + lm;
#pragma unroll
            for (int r = 0; r < 4; ++r)
                C[(size_t)(rowb + r) * N + col] = acc[i][j][r];
        }
}

// ---------------------------------------------------------------------------
// Flash causal attention — EXACT round-4 structure (79.2us, VGPR=128, the
// local optimum: round-5 showed +VGPR pipelining halves occupancy and
// regresses; occupancy plateau is at ~20%). Only delta vs round 4: T5
// s_setprio(1/0) around the QK and PV MFMA clusters (measured +4-7% on
// attn-like kernels, zero register cost).
// ---------------------------------------------------------------------------
__global__ __launch_bounds__(128) void attn_kernel(
    const u16* __restrict__ Qg, const u16* __restrict__ Kg,
    const u16* __restrict__ Vtg, u16* __restrict__ Og)
{
    __shared__ __align__(16) u16 Pl[2 * 64 * 40];    // 10.25KB; reused for combine

    const int tid  = threadIdx.x;
    const int wave = tid >> 6;
    const int lane = tid & 63;
    const int lq = lane >> 4, lm = lane & 15;
    const int id = blockIdx.x;            // 0..2047
    const int xs = id & 7;                // XCD slot
    const int bh = xs + 8 * ((id >> 3) & 7);   // 8 bh per XCD slot
    const int qj = 31 - (id >> 6);        // longest-first dispatch order
    const int b = bh >> 4, h = bh & 15;

    const size_t batchoff = (size_t)b * T_ * D_;
    const size_t headoff  = (size_t)h * DH_;
    const size_t vbase    = (size_t)bh * DH_ * T_;

    u16* pw = Pl + wave * 64 * 40;

    const int qw  = qj * 64;
    const int ktd = qj >> 1;               // diagonal 128-key tile
    const int odd = qj & 1;                // which half of diag tile

    // Q fragments (B-operand): lane holds query qw+qf*16+lm, dh=ks*32+lq*8+j
    bf16x8 aq[4][2];
#pragma unroll
    for (int qf = 0; qf < 4; ++qf) {
        const u16* qrow = Qg + batchoff + (size_t)(qw + qf * 16 + lm) * D_ + headoff;
        aq[qf][0] = *(const bf16x8*)(qrow + lq * 8);
        aq[qf][1] = *(const bf16x8*)(qrow + 32 + lq * 8);
    }

    f32x4 oaccT[4][4] = {};          // [qf][dh-frag]; row=dh, col=query
    float l_lane[4] = {0.f, 0.f, 0.f, 0.f};

    // split-K: wave w handles k-tiles of parity w
#pragma unroll 1
    for (int kt = wave; kt <= ktd; kt += 2) {
        const bool diag = (kt == ktd);
        const int ksmax = diag ? (odd ? 3 : 1) : 3;   // 32-key chunks

#pragma unroll
        for (int c = 0; c < 4; ++c) {
            if (c <= ksmax) {
                // ---- two 16-key fragments: S^T mfma -> mask -> exp2 -> pack ----
#pragma unroll
                for (int t = 0; t < 2; ++t) {
                    const int mt = 2 * c + t;
                    const u16* krow = Kg + batchoff
                        + (size_t)(kt * 128 + mt * 16 + lm) * D_ + headoff;
                    bf16x8 kf0 = *(const bf16x8*)(krow + lq * 8);
                    bf16x8 kf1 = *(const bf16x8*)(krow + 32 + lq * 8);
                    f32x4 s[4];
                    __builtin_amdgcn_s_setprio(1);
#pragma unroll
                    for (int qf = 0; qf < 4; ++qf) {
                        s[qf] = f32x4{0.f, 0.f, 0.f, 0.f};
                        s[qf] = __builtin_amdgcn_mfma_f32_16x16x32_bf16(
                            kf0, aq[qf][0], s[qf], 0, 0, 0);
                        s[qf] = __builtin_amdgcn_mfma_f32_16x16x32_bf16(
                            kf1, aq[qf][1], s[qf], 0, 0, 0);
                    }
                    __builtin_amdgcn_s_setprio(0);
                    if (diag) {
                        int keyb = kt * 128 + mt * 16 + lq * 4;
#pragma unroll
                        for (int qf = 0; qf < 4; ++qf) {
                            int query = qw + qf * 16 + lm;
#pragma unroll
                            for (int r = 0; r < 4; ++r)
                                if (keyb + r > query) s[qf][r] = -1e9f;
                        }
                    }
#pragma unroll
                    for (int qf = 0; qf < 4; ++qf) {
                        float p0 = __builtin_amdgcn_exp2f(s[qf][0]);
                        float p1 = __builtin_amdgcn_exp2f(s[qf][1]);
                        float p2 = __builtin_amdgcn_exp2f(s[qf][2]);
                        float p3 = __builtin_amdgcn_exp2f(s[qf][3]);
                        l_lane[qf] += (p0 + p1) + (p2 + p3);
                        uint2 d; d.x = pack2(p0, p1); d.y = pack2(p2, p3);
                        *(uint2*)(pw + (qf * 16 + lm) * 40 + t * 16 + lq * 4) = d;
                    }
                }
                // same-wave LDS RAW: compiler inserts lgkmcnt waits

                // ---- O^T += V^T P^T for this 32-key chunk ----
                bf16x8 pf[4];
#pragma unroll
                for (int qf = 0; qf < 4; ++qf)
                    pf[qf] = *(const bf16x8*)(pw + (qf * 16 + lm) * 40 + lq * 8);
                __builtin_amdgcn_s_setprio(1);
#pragma unroll
                for (int mo = 0; mo < 4; ++mo) {
                    const u16* vrow = Vtg + vbase
                        + (size_t)(mo * 16 + lm) * T_ + kt * 128 + c * 32;
                    bf16x8 vf = *(const bf16x8*)(vrow + lq * 8);
#pragma unroll
                    for (int qf = 0; qf < 4; ++qf)
                        oaccT[qf][mo] = __builtin_amdgcn_mfma_f32_16x16x32_bf16(
                            vf, pf[qf], oaccT[qf][mo], 0, 0, 0);
                }
                __builtin_amdgcn_s_setprio(0);
            }
        }
    }

    // ---- split-K combine through retired Pl (two 8-slot rounds) ----
    float* Cf = (float*)Pl;                      // 2560 floats
    const int cswz = (lane ^ (lane >> 3)) * 4;   // f32x4 float-offset in slot
    __syncthreads();                             // both waves done with Pl
    if (wave == 1) {
#pragma unroll
        for (int qf = 0; qf < 2; ++qf)
#pragma unroll
            for (int mo = 0; mo < 4; ++mo)
                *(f32x4*)&Cf[(qf * 4 + mo) * 256 + cswz] = oaccT[qf][mo];
#pragma unroll
        for (int qf = 0; qf < 4; ++qf)
            Cf[2048 + qf * 64 + lane] = l_lane[qf];   // l partials (1KB tail)
    }
    __syncthreads();
    if (wave == 0) {
#pragma unroll
        for (int qf = 0; qf < 2; ++qf)
#pragma unroll
            for (int mo = 0; mo < 4; ++mo) {
                f32x4 o = *(const f32x4*)&Cf[(qf * 4 + mo) * 256 + cswz];
#pragma unroll
                for (int r = 0; r < 4; ++r) oaccT[qf][mo][r] += o[r];
            }
#pragma unroll
        for (int qf = 0; qf < 4; ++qf) l_lane[qf] += Cf[2048 + qf * 64 + lane];
    }
    __syncthreads();
    if (wave == 1) {
#pragma unroll
        for (int qf = 2; qf < 4; ++qf)
#pragma unroll
            for (int mo = 0; mo < 4; ++mo)
                *(f32x4*)&Cf[((qf - 2) * 4 + mo) * 256 + cswz] = oaccT[qf][mo];
    }
    __syncthreads();
    if (wave == 0) {
#pragma unroll
        for (int qf = 2; qf < 4; ++qf)
#pragma unroll
            for (int mo = 0; mo < 4; ++mo) {
                f32x4 o = *(const f32x4*)&Cf[((qf - 2) * 4 + mo) * 256 + cswz];
#pragma unroll
                for (int r = 0; r < 4; ++r) oaccT[qf][mo][r] += o[r];
            }
        // epilogue: reduce l across quads, O = O^T / l, packed stores
#pragma unroll
        for (int qf = 0; qf < 4; ++qf) {
            float l = l_lane[qf];
            l += __shfl_xor(l, 16, 64);
            l += __shfl_xor(l, 32, 64);
            float inv = 1.0f / l;
            int row = qw + qf * 16 + lm;
            u16* obase = Og + batchoff + (size_t)row * D_ + headoff;
#pragma unroll
            for (int mo = 0; mo < 4; ++mo) {
                uint2 d;
                d.x = pack2(oaccT[qf][mo][0] * inv, oaccT[qf][mo][1] * inv);
                d.y = pack2(oaccT[qf][mo][2] * inv, oaccT[qf][mo][3] * inv);
                *(uint2*)(obase + mo * 16 + lq * 4) = d;
            }
        }
    }
}

// ---------------------------------------------------------------------------
extern "C" void kernel_launch(void* const* d_in, const int* in_sizes, int n_in,
                              void* d_out, int out_size, void* d_ws, size_t ws_size,
                              hipStream_t stream)
{
    const float* x  = (const float*)d_in[0];   // fp32 (B,T,D)
    // d_in[1] = mask (int32 tril) — causality hardcoded, not read
    const float* Wq = (const float*)d_in[2];   // fp32 (D,D)
    const float* Wk = (const float*)d_in[3];
    const float* Wv = (const float*)d_in[4];
    const float* Wo = (const float*)d_in[5];

    const size_t DD = (size_t)D_ * D_;
    u16* Qb  = (u16*)d_ws;        // Q (scaled), K, V(trans) contiguous
    u16* Kb  = Qb + NT_;
    u16* Vb  = Kb + NT_;
    u16* Ob  = Vb + NT_;
    u16* xb  = Ob + NT_;
    u16* wb  = xb + NT_;          // 4 x DD: Wq, Wk, Wv, Wo

    const int M = B_ * T_;        // 8192

    cvt_x_kernel<<<dim3((int)(NT_ / 8 / 256)), 256, 0, stream>>>(x, xb, (int)(NT_ / 8));
    cvt_w_kernel<<<dim3((int)(DD / 8 / 256), 4), 256, 0, stream>>>(Wq, Wk, Wv, Wo, wb);

    // fused Q/K/V projection: x @ [Wq;Wk;Wv]^T, N=3072, routed epilogue
    // 256x192 tile, 8 waves, read-pipelined: grid = 32*16 = 512 blocks
    gemm8_kernel<3><<<dim3((M / 256) * (3 * D_ / 192)), 512, 0, stream>>>(
        xb, wb, Qb, M, 3 * D_, D_);

    // split-K (2 waves/block) attention: 2048 blocks x 128 thr (1 q-tile each),
    // longest-first, XCD-swizzled (round-4 structure + setprio)
    attn_kernel<<<dim3(2048), 128, 0, stream>>>(Qb, Kb, Vb, Ob);

    // output projection -> fp32: 256x128 tile, 256 blocks = 1 full round
    gemm8o_kernel<<<dim3(256), 512, 0, stream>>>(Ob, wb + 3 * DD, (float*)d_out);
}

// Round 7
// 268.763 us; speedup vs baseline: 1.0281x; 1.0021x over previous
//
#include <hip/hip_runtime.h>
#include <stdint.h>

// Problem constants: B=4, T=2048, D=1024, H=16, DH=64
#define B_  4
#define T_  2048
#define D_  1024
#define H_  16
#define DH_ 64

typedef unsigned short u16;
typedef __attribute__((ext_vector_type(8))) short bf16x8;   // 8 bf16 = 4 VGPRs
typedef __attribute__((ext_vector_type(8))) unsigned short u16x8;
typedef __attribute__((ext_vector_type(4))) unsigned short u16x4;
typedef __attribute__((ext_vector_type(4))) float f32x4;

#define NT_ ((size_t)B_ * T_ * D_)          // 8.4M elements
#define QSCALE 0.18033688011112043f         // log2(e)/sqrt(DH): exp2-domain softmax

__device__ __forceinline__ u16 f2bf(float f) {
    union { float f; uint32_t u; } v; v.f = f;
    uint32_t r = v.u + 0x7FFFu + ((v.u >> 16) & 1u);   // RNE
    return (u16)(r >> 16);
}

// pack two fp32 into one dword of 2 bf16 (truncation) — single v_perm_b32
__device__ __forceinline__ uint32_t pack2(float lo, float hi) {
    union { float f; uint32_t u; } a, b; a.f = lo; b.f = hi;
    return __builtin_amdgcn_perm(b.u, a.u, 0x07060302u);
}

// async 16B global->LDS (lds dest is wave-uniform; HW adds lane*16)
__device__ __forceinline__ void gl2lds16(const u16* g, u16* l) {
    __builtin_amdgcn_global_load_lds(
        (const __attribute__((address_space(1))) unsigned int*)g,
        (__attribute__((address_space(3))) unsigned int*)l,
        16, 0, 0);
}

#define VMCNT(n) asm volatile("s_waitcnt vmcnt(" #n ")" ::: "memory")
#define LGKM0()  asm volatile("s_waitcnt lgkmcnt(0)" ::: "memory")
#define SB0()    __builtin_amdgcn_sched_barrier(0)

// swizzled LDS fragment read: row in element-rows (128B stride), ks selects
// 32-elem K-half, lq*16B within; swzr = (lm&7)<<4 XOR (matches staging layout)
__device__ __forceinline__ bf16x8 ldsrd(const u16* base, int row, int ks,
                                        int lq, int swzr) {
    int off = row * 128 + ks * 64 + lq * 16;   // bytes
    return *(const bf16x8*)((const char*)base + (off ^ swzr));
}

// ---------------------------------------------------------------------------
// fp32 -> bf16 converters
// ---------------------------------------------------------------------------
__global__ __launch_bounds__(256) void cvt_x_kernel(
    const float* __restrict__ src, u16* __restrict__ dst, int n8)
{
    int i = blockIdx.x * 256 + threadIdx.x;
    if (i >= n8) return;
    f32x4 a = ((const f32x4*)src)[2 * i];
    f32x4 b = ((const f32x4*)src)[2 * i + 1];
    u16x8 o;
    o[0]=f2bf(a[0]); o[1]=f2bf(a[1]); o[2]=f2bf(a[2]); o[3]=f2bf(a[3]);
    o[4]=f2bf(b[0]); o[5]=f2bf(b[1]); o[6]=f2bf(b[2]); o[7]=f2bf(b[3]);
    ((u16x8*)dst)[i] = o;
}

__global__ __launch_bounds__(256) void cvt_w_kernel(
    const float* __restrict__ w0, const float* __restrict__ w1,
    const float* __restrict__ w2, const float* __restrict__ w3,
    u16* __restrict__ dst)   // 4 consecutive D*D segments: Wq,Wk,Wv,Wo
{
    const float* src = (blockIdx.y == 0) ? w0 : (blockIdx.y == 1) ? w1
                     : (blockIdx.y == 2) ? w2 : w3;
    u16* d = dst + (size_t)blockIdx.y * (D_ * D_);
    int i = blockIdx.x * 256 + threadIdx.x;
    f32x4 a = ((const f32x4*)src)[2 * i];
    f32x4 b = ((const f32x4*)src)[2 * i + 1];
    u16x8 o;
    o[0]=f2bf(a[0]); o[1]=f2bf(a[1]); o[2]=f2bf(a[2]); o[3]=f2bf(a[3]);
    o[4]=f2bf(b[0]); o[5]=f2bf(b[1]); o[6]=f2bf(b[2]); o[7]=f2bf(b[3]);
    ((u16x8*)d)[i] = o;
}

// ---------------------------------------------------------------------------
// QKV GEMM: C[M,N] = X[M,K] @ W[N,K]^T — 256x192 tile, 8 waves (2M x 4N),
// BK=64. ROUND-7: 2 FAT PHASES per K-tile (was 4 thin ones).
// Round-6 counters: 1790 cy/phase vs 466 cy MFMA — ~1320 cy of roughly
// CONSTANT per-phase sync overhead (2 barriers x 8-wave skew + waits).
// Amortize: halve phase count, double MFMA per phase (24/wave, 931cy/SIMD —
// now the longest pole). m201-faithful phase: {ds_read frags + issue stage
// -> barrier -> lgkmcnt(0) -> SB0 -> setprio(1) MFMA setprio(0) -> barrier}.
// Fragment ping-pong registers eliminated (read-and-use in phase): ~-40 VGPR.
//
// Per K-tile t:
//  P0 (i=0..3): read af(8) + bq(6); stage A[t+1]h0 (2 DMA)
//  P1 (i=4..7): read af(8);         stage A[t+1]h1 (2) + B[t+2] (3 DMA)
//     end-P1: VMCNT(3)  -> A[t+1],B[t+1] landed; B[t+2] (newest 3) in flight
// WAR: A-stage at t.P0 into Ab2[(t+1)&1] — tile t-1's last reads of that
//   buffer were lgkm-drained before t-1.P1's MFMA, >=1 barrier earlier. OK.
//   B-stage at t.P1 into Bb2[t&1] — bq reads of it (t.P0) drained before
//   P0's MFMA + trailing barrier. OK (bq values live in registers).
// RAW: vmcnt(3) at t.P1-end leaves only B[t+2] in flight -> t+1.P0's reads
//   of A[t+1]/B[t+1] are safe after the trailing barrier.
// OUT_MODE 3 = fused QKV routing (Q scaled / K / V^T).
// ---------------------------------------------------------------------------
template<int OUT_MODE>
__global__ __launch_bounds__(512) void gemm8_kernel(
    const u16* __restrict__ X, const u16* __restrict__ W,
    void* __restrict__ C, int M, int N, int K)
{
    __shared__ __align__(16) u16 Ab2[2][256 * 64];   // 64 KB
    __shared__ __align__(16) u16 Bb2[2][192 * 64];   // 48 KB

    const int tid  = threadIdx.x;
    const int wave = tid >> 6;
    const int lane = tid & 63;
    const int lq = lane >> 4, lm = lane & 15;
    const int wm = wave >> 2;      // wave's M slot (0..1) -> 128 rows
    const int wn = wave & 3;       // wave's N slot (0..3) -> 48 cols

    // rect XCD swizzle: XCD (bid&7) owns an 8x8 tile rectangle
    const int xcd = (int)blockIdx.x & 7;
    const int idx = (int)blockIdx.x >> 3;   // 0..63
    const int m0 = (((xcd & 3) << 3) + (idx & 7)) << 8;      // 32 M-tiles
    const int n0 = (((xcd >> 2) << 3) + (idx >> 3)) * 192;   // 16 N-tiles

    // staging: each gl2lds covers 64 rows (512thr x 16B = 8KB); 16B chunk
    // scol pre-swizzled so LINEAR LDS DMA writes land in swizzled layout.
    const int srow = wave * 8 + (lane >> 3);                 // 0..63
    const int scol = ((lane & 7) ^ (lane >> 3)) << 3;        // elements
    const u16* gA = X + (size_t)(m0 + srow) * K + scol;
    const u16* gB = W + (size_t)(n0 + srow) * K + scol;
    const size_t rK64 = (size_t)64 * K;

    const int swzr = (lm & 7) << 4;        // ds_read byte-address XOR

    f32x4 acc[8][3] = {};                  // 96 AGPR
    const int NT = K >> 6;                 // 16

    // ---- prologue: stage A0(4), B0(3), B1(3) ----
    gl2lds16(gA,            (u16*)Ab2[0] + wave * 512);
    gl2lds16(gA + rK64,     (u16*)Ab2[0] + 4096  + wave * 512);
    gl2lds16(gA + 2 * rK64, (u16*)Ab2[0] + 8192  + wave * 512);
    gl2lds16(gA + 3 * rK64, (u16*)Ab2[0] + 12288 + wave * 512);
    gl2lds16(gB,            (u16*)Bb2[0] + wave * 512);
    gl2lds16(gB + rK64,     (u16*)Bb2[0] + 4096  + wave * 512);
    gl2lds16(gB + 2 * rK64, (u16*)Bb2[0] + 8192  + wave * 512);
    gl2lds16(gB + 64,            (u16*)Bb2[1] + wave * 512);
    gl2lds16(gB + 64 + rK64,     (u16*)Bb2[1] + 4096  + wave * 512);
    gl2lds16(gB + 64 + 2 * rK64, (u16*)Bb2[1] + 8192  + wave * 512);
    VMCNT(3);                               // A0,B0 landed; B1 (3) in flight
    __builtin_amdgcn_s_barrier();

#define MFMA_HALF(IOFF)                                                     \
        __builtin_amdgcn_s_setprio(1);                                      \
        _Pragma("unroll")                                                   \
        for (int ks = 0; ks < 2; ++ks)                                      \
            _Pragma("unroll")                                               \
            for (int i4 = 0; i4 < 4; ++i4)                                  \
                _Pragma("unroll")                                           \
                for (int j = 0; j < 3; ++j)                                 \
                    acc[(IOFF) + i4][j] =                                   \
                        __builtin_amdgcn_mfma_f32_16x16x32_bf16(            \
                            af[i4][ks], bq[j][ks], acc[(IOFF) + i4][j],     \
                            0, 0, 0);                                       \
        __builtin_amdgcn_s_setprio(0);

#pragma unroll 1
    for (int t = 0; t < NT; ++t) {
        const u16* Ac = Ab2[t & 1];
        const u16* Bc = Bb2[t & 1];
        u16* Abn = (u16*)Ab2[(t + 1) & 1];
        u16* Bbc = (u16*)Bb2[t & 1];
        const bool stA = (t + 1 < NT);
        const bool stB = (t + 2 < NT);
        const u16* gAs = gA + (size_t)(t + 1) * 64;
        const u16* gBs = gB + (size_t)(t + 2) * 64;

        bf16x8 af[4][2], bq[3][2];

        // ---- P0: quadrants i=0..3; bq for whole tile ----
#pragma unroll
        for (int i4 = 0; i4 < 4; ++i4)
#pragma unroll
            for (int ks = 0; ks < 2; ++ks)
                af[i4][ks] = ldsrd(Ac, wm * 128 + i4 * 16 + lm, ks, lq, swzr);
#pragma unroll
        for (int j = 0; j < 3; ++j)
#pragma unroll
            for (int ks = 0; ks < 2; ++ks)
                bq[j][ks] = ldsrd(Bc, wn * 48 + j * 16 + lm, ks, lq, swzr);
        if (stA) {
            gl2lds16(gAs,        Abn + wave * 512);
            gl2lds16(gAs + rK64, Abn + 4096 + wave * 512);
        }
        SB0(); __builtin_amdgcn_s_barrier();
        LGKM0(); SB0();
        MFMA_HALF(0)
        SB0(); __builtin_amdgcn_s_barrier();

        // ---- P1: quadrants i=4..7 ----
#pragma unroll
        for (int i4 = 0; i4 < 4; ++i4)
#pragma unroll
            for (int ks = 0; ks < 2; ++ks)
                af[i4][ks] = ldsrd(Ac, wm * 128 + (4 + i4) * 16 + lm, ks, lq, swzr);
        if (stA) {
            gl2lds16(gAs + 2 * rK64, Abn + 8192  + wave * 512);
            gl2lds16(gAs + 3 * rK64, Abn + 12288 + wave * 512);
        }
        if (stB) {
            gl2lds16(gBs,            Bbc + wave * 512);
            gl2lds16(gBs + rK64,     Bbc + 4096 + wave * 512);
            gl2lds16(gBs + 2 * rK64, Bbc + 8192 + wave * 512);
        }
        SB0(); __builtin_amdgcn_s_barrier();
        LGKM0(); SB0();
        MFMA_HALF(4)
        SB0();
        if (stB)      { VMCNT(3); }   // A[t+1],B[t+1] landed; B[t+2] in flight
        else if (stA) { VMCNT(0); }   // t==NT-2: drain A[NT-1]
        __builtin_amdgcn_s_barrier();
    }
#undef MFMA_HALF

    // ---- epilogue: acc[i][j][r] -> row m0+wm*128+i*16+lq*4+r,
    //                               col n0+wn*48+j*16+lm ----
#pragma unroll
    for (int i = 0; i < 8; ++i)
#pragma unroll
        for (int j = 0; j < 3; ++j) {
            int rowb = m0 + wm * 128 + i * 16 + lq * 4;
            int col  = n0 + wn * 48 + j * 16 + lm;
            if (OUT_MODE == 2) {
#pragma unroll
                for (int r = 0; r < 4; ++r)
                    ((float*)C)[(size_t)(rowb + r) * N + col] = acc[i][j][r];
            } else {
                u16* Qp = (u16*)C;
                int region = col >> 10;      // per-fragment: 192 tile straddles
                int colr = col & 1023;
                if (region == 0) {
#pragma unroll
                    for (int r = 0; r < 4; ++r)
                        Qp[(size_t)(rowb + r) * D_ + colr] = f2bf(acc[i][j][r] * QSCALE);
                } else if (region == 1) {
#pragma unroll
                    for (int r = 0; r < 4; ++r)
                        (Qp + NT_)[(size_t)(rowb + r) * D_ + colr] = f2bf(acc[i][j][r]);
                } else {
                    int b = rowb >> 11, tt2 = rowb & (T_ - 1);   // 4 consecutive t
                    u16x4 pk;
#pragma unroll
                    for (int r = 0; r < 4; ++r) pk[r] = f2bf(acc[i][j][r]);
                    *(u16x4*)((Qp + 2 * NT_) + ((size_t)b * D_ + colr) * T_ + tt2) = pk;
                }
            }
        }
}

// ---------------------------------------------------------------------------
// Out-projection GEMM: 256x128 tile, 8 waves, read-pipelined 4-phase
// schedule (unchanged from round 6 — worked; not in top-5).
// ---------------------------------------------------------------------------
__global__ __launch_bounds__(512) void gemm8o_kernel(
    const u16* __restrict__ X, const u16* __restrict__ W,
    float* __restrict__ C)    // M=8192, N=1024, K=1024
{
    __shared__ __align__(16) u16 Ab2[2][256 * 64];   // 64 KB
    __shared__ __align__(16) u16 Bb2[2][128 * 64];   // 32 KB

    const int K = 1024, N = 1024;
    const int tid  = threadIdx.x;
    const int wave = tid >> 6;
    const int lane = tid & 63;
    const int lq = lane >> 4, lm = lane & 15;
    const int wm = wave >> 2;      // 0..1 -> 128 rows
    const int wn = wave & 3;       // 0..3 -> 32 cols

    // rect XCD swizzle: XCD owns an 8x4 tile rectangle (32 M-tiles, 8 N-tiles)
    const int xcd = (int)blockIdx.x & 7;
    const int idx = (int)blockIdx.x >> 3;   // 0..31
    const int m0 = (((xcd & 3) << 3) + (idx & 7)) << 8;
    const int n0 = (((xcd >> 2) << 2) + (idx >> 3)) << 7;

    const int srow = wave * 8 + (lane >> 3);                 // 0..63
    const int scol = ((lane & 7) ^ (lane >> 3)) << 3;        // elements
    const u16* gA = X + (size_t)(m0 + srow) * K + scol;
    const u16* gB = W + (size_t)(n0 + srow) * K + scol;
    const size_t rK64 = (size_t)64 * K;

    const int swzr = (lm & 7) << 4;

    f32x4 acc[8][2] = {};                  // 64 AGPR
    bf16x8 afA[2][2], afB[2][2];
    bf16x8 bqA[2][2], bqB[2][2];
    const int NT = 16;

    // ---- prologue: stage A0(4), B0(2), B1(2) ----
    gl2lds16(gA,            (u16*)Ab2[0] + wave * 512);
    gl2lds16(gA + rK64,     (u16*)Ab2[0] + 4096  + wave * 512);
    gl2lds16(gA + 2 * rK64, (u16*)Ab2[0] + 8192  + wave * 512);
    gl2lds16(gA + 3 * rK64, (u16*)Ab2[0] + 12288 + wave * 512);
    gl2lds16(gB,            (u16*)Bb2[0] + wave * 512);
    gl2lds16(gB + rK64,     (u16*)Bb2[0] + 4096  + wave * 512);
    gl2lds16(gB + 64,            (u16*)Bb2[1] + wave * 512);
    gl2lds16(gB + 64 + rK64,     (u16*)Bb2[1] + 4096  + wave * 512);
    VMCNT(2);                               // A0,B0 landed; B1 (2) in flight
    __builtin_amdgcn_s_barrier();
#pragma unroll
    for (int i2 = 0; i2 < 2; ++i2)
#pragma unroll
        for (int ks = 0; ks < 2; ++ks)
            afA[i2][ks] = ldsrd(Ab2[0], wm * 128 + i2 * 16 + lm, ks, lq, swzr);
#pragma unroll
    for (int j = 0; j < 2; ++j)
#pragma unroll
        for (int ks = 0; ks < 2; ++ks)
            bqA[j][ks] = ldsrd(Bb2[0], wn * 32 + j * 16 + lm, ks, lq, swzr);

    auto tile_body = [&](int t, bf16x8 (&bqU)[2][2], bf16x8 (&bqF)[2][2])
        __attribute__((always_inline)) -> void {
        const u16* Ac = Ab2[t & 1];
        const u16* An = Ab2[(t + 1) & 1];
        const u16* Bn = Bb2[(t + 1) & 1];
        u16* Abn = (u16*)Ab2[(t + 1) & 1];
        u16* Bbc = (u16*)Bb2[t & 1];
        const bool stA = (t + 1 < NT);
        const bool stB = (t + 2 < NT);
        const u16* gAs = gA + (size_t)(t + 1) * 64;
        const u16* gBs = gB + (size_t)(t + 2) * 64;

#define MFMA_PHO(Q, AF, BQ)                                                 \
        __builtin_amdgcn_s_setprio(1);                                      \
        _Pragma("unroll")                                                   \
        for (int ks = 0; ks < 2; ++ks)                                      \
            _Pragma("unroll")                                               \
            for (int i2 = 0; i2 < 2; ++i2)                                  \
                _Pragma("unroll")                                           \
                for (int j = 0; j < 2; ++j)                                 \
                    acc[2 * (Q) + i2][j] =                                  \
                        __builtin_amdgcn_mfma_f32_16x16x32_bf16(            \
                            AF[i2][ks], BQ[j][ks], acc[2 * (Q) + i2][j],    \
                            0, 0, 0);                                       \
        __builtin_amdgcn_s_setprio(0);

#define RD_AFO(SET, P, BASE)                                                \
        _Pragma("unroll")                                                   \
        for (int i2 = 0; i2 < 2; ++i2)                                      \
            _Pragma("unroll")                                               \
            for (int ks = 0; ks < 2; ++ks)                                  \
                SET[i2][ks] = ldsrd(BASE,                                   \
                    wm * 128 + (2 * (P) + i2) * 16 + lm, ks, lq, swzr);

        // ---- phase 0 ----
        RD_AFO(afB, 1, Ac);
        if (stA) {
            gl2lds16(gAs,        Abn + wave * 512);
            gl2lds16(gAs + rK64, Abn + 4096 + wave * 512);
        }
        SB0(); __builtin_amdgcn_s_barrier(); SB0();
        MFMA_PHO(0, afA, bqU); SB0();
        __builtin_amdgcn_s_barrier();

        // ---- phase 1 ----
        RD_AFO(afA, 2, Ac);
        if (stA) {
            gl2lds16(gAs + 2 * rK64, Abn + 8192  + wave * 512);
            gl2lds16(gAs + 3 * rK64, Abn + 12288 + wave * 512);
        }
        SB0(); __builtin_amdgcn_s_barrier(); SB0();
        MFMA_PHO(1, afB, bqU); SB0();
        __builtin_amdgcn_s_barrier();

        // ---- phase 2 ----
        RD_AFO(afB, 3, Ac);
        if (stB)
            gl2lds16(gBs, Bbc + wave * 512);
        SB0(); __builtin_amdgcn_s_barrier(); SB0();
        MFMA_PHO(2, afA, bqU); SB0();
        if (stB)      { VMCNT(1); }   // B[t+1]+A[t+1] landed; B[t+2]h0 in flight
        else if (stA) { VMCNT(0); }   // t==NT-2: drain A[NT-1] (+B tail)
        __builtin_amdgcn_s_barrier();

        // ---- phase 3 ----
        if (stA) {
            RD_AFO(afA, 0, An);
#pragma unroll
            for (int j = 0; j < 2; ++j)
#pragma unroll
                for (int ks = 0; ks < 2; ++ks)
                    bqF[j][ks] = ldsrd(Bn, wn * 32 + j * 16 + lm, ks, lq, swzr);
        }
        if (stB)
            gl2lds16(gBs + rK64, Bbc + 4096 + wave * 512);
        SB0(); __builtin_amdgcn_s_barrier(); SB0();
        MFMA_PHO(3, afB, bqU); SB0();
        __builtin_amdgcn_s_barrier();
#undef RD_AFO
#undef MFMA_PHO
    };

#pragma unroll 1
    for (int tt = 0; tt < NT; tt += 2) {
        tile_body(tt,     bqA, bqB);
        tile_body(tt + 1, bqB, bqA);
    }

    // ---- epilogue: fp32 natural ----
#pragma unroll
    for (int i = 0; i < 8; ++i)
#pragma unroll
        for (int j = 0; j < 2; ++j) {
            int rowb = m0 + wm * 128 + i * 16 + lq * 4;
            int col  = n0 + wn * 32 + j * 16 + lm;
#pragma unroll
            for (int r = 0; r < 4; ++r)
                C[(size_t)(rowb + r) * N + col] = acc[i][j][r];
        }
}

// ---------------------------------------------------------------------------
// Flash causal attention — round-4 structure + setprio (unchanged from
// round 6; VGPR=128 local optimum, ~20% occupancy plateau).
// ---------------------------------------------------------------------------
__global__ __launch_bounds__(128) void attn_kernel(
    const u16* __restrict__ Qg, const u16* __restrict__ Kg,
    const u16* __restrict__ Vtg, u16* __restrict__ Og)
{
    __shared__ __align__(16) u16 Pl[2 * 64 * 40];    // 10.25KB; reused for combine

    const int tid  = threadIdx.x;
    const int wave = tid >> 6;
    const int lane = tid & 63;
    const int lq = lane >> 4, lm = lane & 15;
    const int id = blockIdx.x;            // 0..2047
    const int xs = id & 7;                // XCD slot
    const int bh = xs + 8 * ((id >> 3) & 7);   // 8 bh per XCD slot
    const int qj = 31 - (id >> 6);        // longest-first dispatch order
    const int b = bh >> 4, h = bh & 15;

    const size_t batchoff = (size_t)b * T_ * D_;
    const size_t headoff  = (size_t)h * DH_;
    const size_t vbase    = (size_t)bh * DH_ * T_;

    u16* pw = Pl + wave * 64 * 40;

    const int qw  = qj * 64;
    const int ktd = qj >> 1;               // diagonal 128-key tile
    const int odd = qj & 1;                // which half of diag tile

    // Q fragments (B-operand): lane holds query qw+qf*16+lm, dh=ks*32+lq*8+j
    bf16x8 aq[4][2];
#pragma unroll
    for (int qf = 0; qf < 4; ++qf) {
        const u16* qrow = Qg + batchoff + (size_t)(qw + qf * 16 + lm) * D_ + headoff;
        aq[qf][0] = *(const bf16x8*)(qrow + lq * 8);
        aq[qf][1] = *(const bf16x8*)(qrow + 32 + lq * 8);
    }

    f32x4 oaccT[4][4] = {};          // [qf][dh-frag]; row=dh, col=query
    float l_lane[4] = {0.f, 0.f, 0.f, 0.f};

    // split-K: wave w handles k-tiles of parity w
#pragma unroll 1
    for (int kt = wave; kt <= ktd; kt += 2) {
        const bool diag = (kt == ktd);
        const int ksmax = diag ? (odd ? 3 : 1) : 3;   // 32-key chunks

#pragma unroll
        for (int c = 0; c < 4; ++c) {
            if (c <= ksmax) {
                // ---- two 16-key fragments: S^T mfma -> mask -> exp2 -> pack ----
#pragma unroll
                for (int t = 0; t < 2; ++t) {
                    const int mt = 2 * c + t;
                    const u16* krow = Kg + batchoff
                        + (size_t)(kt * 128 + mt * 16 + lm) * D_ + headoff;
                    bf16x8 kf0 = *(const bf16x8*)(krow + lq * 8);
                    bf16x8 kf1 = *(const bf16x8*)(krow + 32 + lq * 8);
                    f32x4 s[4];
                    __builtin_amdgcn_s_setprio(1);
#pragma unroll
                    for (int qf = 0; qf < 4; ++qf) {
                        s[qf] = f32x4{0.f, 0.f, 0.f, 0.f};
                        s[qf] = __builtin_amdgcn_mfma_f32_16x16x32_bf16(
                            kf0, aq[qf][0], s[qf], 0, 0, 0);
                        s[qf] = __builtin_amdgcn_mfma_f32_16x16x32_bf16(
                            kf1, aq[qf][1], s[qf], 0, 0, 0);
                    }
                    __builtin_amdgcn_s_setprio(0);
                    if (diag) {
                        int keyb = kt * 128 + mt * 16 + lq * 4;
#pragma unroll
                        for (int qf = 0; qf < 4; ++qf) {
                            int query = qw + qf * 16 + lm;
#pragma unroll
                            for (int r = 0; r < 4; ++r)
                                if (keyb + r > query) s[qf][r] = -1e9f;
                        }
                    }
#pragma unroll
                    for (int qf = 0; qf < 4; ++qf) {
                        float p0 = __builtin_amdgcn_exp2f(s[qf][0]);
                        float p1 = __builtin_amdgcn_exp2f(s[qf][1]);
                        float p2 = __builtin_amdgcn_exp2f(s[qf][2]);
                        float p3 = __builtin_amdgcn_exp2f(s[qf][3]);
                        l_lane[qf] += (p0 + p1) + (p2 + p3);
                        uint2 d; d.x = pack2(p0, p1); d.y = pack2(p2, p3);
                        *(uint2*)(pw + (qf * 16 + lm) * 40 + t * 16 + lq * 4) = d;
                    }
                }
                // same-wave LDS RAW: compiler inserts lgkmcnt waits

                // ---- O^T += V^T P^T for this 32-key chunk ----
                bf16x8 pf[4];
#pragma unroll
                for (int qf = 0; qf < 4; ++qf)
                    pf[qf] = *(const bf16x8*)(pw + (qf * 16 + lm) * 40 + lq * 8);
                __builtin_amdgcn_s_setprio(1);
#pragma unroll
                for (int mo = 0; mo < 4; ++mo) {
                    const u16* vrow = Vtg + vbase
                        + (size_t)(mo * 16 + lm) * T_ + kt * 128 + c * 32;
                    bf16x8 vf = *(const bf16x8*)(vrow + lq * 8);
#pragma unroll
                    for (int qf = 0; qf < 4; ++qf)
                        oaccT[qf][mo] = __builtin_amdgcn_mfma_f32_16x16x32_bf16(
                            vf, pf[qf], oaccT[qf][mo], 0, 0, 0);
                }
                __builtin_amdgcn_s_setprio(0);
            }
        }
    }

    // ---- split-K combine through retired Pl (two 8-slot rounds) ----
    float* Cf = (float*)Pl;                      // 2560 floats
    const int cswz = (lane ^ (lane >> 3)) * 4;   // f32x4 float-offset in slot
    __syncthreads();                             // both waves done with Pl
    if (wave == 1) {
#pragma unroll
        for (int qf = 0; qf < 2; ++qf)
#pragma unroll
            for (int mo = 0; mo < 4; ++mo)
                *(f32x4*)&Cf[(qf * 4 + mo) * 256 + cswz] = oaccT[qf][mo];
#pragma unroll
        for (int qf = 0; qf < 4; ++qf)
            Cf[2048 + qf * 64 + lane] = l_lane[qf];   // l partials (1KB tail)
    }
    __syncthreads();
    if (wave == 0) {
#pragma unroll
        for (int qf = 0; qf < 2; ++qf)
#pragma unroll
            for (int mo = 0; mo < 4; ++mo) {
                f32x4 o = *(const f32x4*)&Cf[(qf * 4 + mo) * 256 + cswz];
#pragma unroll
                for (int r = 0; r < 4; ++r) oaccT[qf][mo][r] += o[r];
            }
#pragma unroll
        for (int qf = 0; qf < 4; ++qf) l_lane[qf] += Cf[2048 + qf * 64 + lane];
    }
    __syncthreads();
    if (wave == 1) {
#pragma unroll
        for (int qf = 2; qf < 4; ++qf)
#pragma unroll
            for (int mo = 0; mo < 4; ++mo)
                *(f32x4*)&Cf[((qf - 2) * 4 + mo) * 256 + cswz] = oaccT[qf][mo];
    }
    __syncthreads();
    if (wave == 0) {
#pragma unroll
        for (int qf = 2; qf < 4; ++qf)
#pragma unroll
            for (int mo = 0; mo < 4; ++mo) {
                f32x4 o = *(const f32x4*)&Cf[((qf - 2) * 4 + mo) * 256 + cswz];
#pragma unroll
                for (int r = 0; r < 4; ++r) oaccT[qf][mo][r] += o[r];
            }
        // epilogue: reduce l across quads, O = O^T / l, packed stores
#pragma unroll
        for (int qf = 0; qf < 4; ++qf) {
            float l = l_lane[qf];
            l += __shfl_xor(l, 16, 64);
            l += __shfl_xor(l, 32, 64);
            float inv = 1.0f / l;
            int row = qw + qf * 16 + lm;
            u16* obase = Og + batchoff + (size_t)row * D_ + headoff;
#pragma unroll
            for (int mo = 0; mo < 4; ++mo) {
                uint2 d;
                d.x = pack2(oaccT[qf][mo][0] * inv, oaccT[qf][mo][1] * inv);
                d.y = pack2(oaccT[qf][mo][2] * inv, oaccT[qf][mo][3] * inv);
                *(uint2*)(obase + mo * 16 + lq * 4) = d;
            }
        }
    }
}

// ---------------------------------------------------------------------------
extern "C" void kernel_launch(void* const* d_in, const int* in_sizes, int n_in,
                              void* d_out, int out_size, void* d_ws, size_t ws_size,
                              hipStream_t stream)
{
    const float* x  = (const float*)d_in[0];   // fp32 (B,T,D)
    // d_in[1] = mask (int32 tril) — causality hardcoded, not read
    const float* Wq = (const float*)d_in[2];   // fp32 (D,D)
    const float* Wk = (const float*)d_in[3];
    const float* Wv = (const float*)d_in[4];
    const float* Wo = (const float*)d_in[5];

    const size_t DD = (size_t)D_ * D_;
    u16* Qb  = (u16*)d_ws;        // Q (scaled), K, V(trans) contiguous
    u16* Kb  = Qb + NT_;
    u16* Vb  = Kb + NT_;
    u16* Ob  = Vb + NT_;
    u16* xb  = Ob + NT_;
    u16* wb  = xb + NT_;          // 4 x DD: Wq, Wk, Wv, Wo

    const int M = B_ * T_;        // 8192

    cvt_x_kernel<<<dim3((int)(NT_ / 8 / 256)), 256, 0, stream>>>(x, xb, (int)(NT_ / 8));
    cvt_w_kernel<<<dim3((int)(DD / 8 / 256), 4), 256, 0, stream>>>(Wq, Wk, Wv, Wo, wb);

    // fused Q/K/V projection: x @ [Wq;Wk;Wv]^T, N=3072, routed epilogue
    // 256x192 tile, 8 waves, 2 fat phases/K-tile: grid = 32*16 = 512 blocks
    gemm8_kernel<3><<<dim3((M / 256) * (3 * D_ / 192)), 512, 0, stream>>>(
        xb, wb, Qb, M, 3 * D_, D_);

    // split-K (2 waves/block) attention: 2048 blocks x 128 thr (1 q-tile each),
    // longest-first, XCD-swizzled (round-4 structure + setprio)
    attn_kernel<<<dim3(2048), 128, 0, stream>>>(Qb, Kb, Vb, Ob);

    // output projection -> fp32: 256x128 tile, 256 blocks = 1 full round
    gemm8o_kernel<<<dim3(256), 512, 0, stream>>>(Ob, wb + 3 * DD, (float*)d_out);
}

// Round 8
// 267.141 us; speedup vs baseline: 1.0344x; 1.0061x over previous
//
#include <hip/hip_runtime.h>
#include <stdint.h>

// Problem constants: B=4, T=2048, D=1024, H=16, DH=64
#define B_  4
#define T_  2048
#define D_  1024
#define H_  16
#define DH_ 64

typedef unsigned short u16;
typedef __attribute__((ext_vector_type(8))) short bf16x8;   // 8 bf16 = 4 VGPRs
typedef __attribute__((ext_vector_type(8))) unsigned short u16x8;
typedef __attribute__((ext_vector_type(4))) unsigned short u16x4;
typedef __attribute__((ext_vector_type(4))) float f32x4;

#define NT_ ((size_t)B_ * T_ * D_)          // 8.4M elements
#define QSCALE 0.18033688011112043f         // log2(e)/sqrt(DH): exp2-domain softmax

__device__ __forceinline__ u16 f2bf(float f) {
    union { float f; uint32_t u; } v; v.f = f;
    uint32_t r = v.u + 0x7FFFu + ((v.u >> 16) & 1u);   // RNE
    return (u16)(r >> 16);
}

// pack two fp32 into one dword of 2 bf16 (truncation) — single v_perm_b32
__device__ __forceinline__ uint32_t pack2(float lo, float hi) {
    union { float f; uint32_t u; } a, b; a.f = lo; b.f = hi;
    return __builtin_amdgcn_perm(b.u, a.u, 0x07060302u);
}

// async 16B global->LDS (lds dest is wave-uniform; HW adds lane*16)
__device__ __forceinline__ void gl2lds16(const u16* g, u16* l) {
    __builtin_amdgcn_global_load_lds(
        (const __attribute__((address_space(1))) unsigned int*)g,
        (__attribute__((address_space(3))) unsigned int*)l,
        16, 0, 0);
}

#define VMCNT(n) asm volatile("s_waitcnt vmcnt(" #n ")" ::: "memory")
#define LGKM0()  asm volatile("s_waitcnt lgkmcnt(0)" ::: "memory")
#define SB0()    __builtin_amdgcn_sched_barrier(0)

// swizzled LDS fragment read: row in element-rows (128B stride), ks selects
// 32-elem K-half, lq*16B within; swzr = (lm&7)<<4 XOR (matches staging layout)
__device__ __forceinline__ bf16x8 ldsrd(const u16* base, int row, int ks,
                                        int lq, int swzr) {
    int off = row * 128 + ks * 64 + lq * 16;   // bytes
    return *(const bf16x8*)((const char*)base + (off ^ swzr));
}

// ---------------------------------------------------------------------------
// fp32 -> bf16 converters
// ---------------------------------------------------------------------------
__global__ __launch_bounds__(256) void cvt_x_kernel(
    const float* __restrict__ src, u16* __restrict__ dst, int n8)
{
    int i = blockIdx.x * 256 + threadIdx.x;
    if (i >= n8) return;
    f32x4 a = ((const f32x4*)src)[2 * i];
    f32x4 b = ((const f32x4*)src)[2 * i + 1];
    u16x8 o;
    o[0]=f2bf(a[0]); o[1]=f2bf(a[1]); o[2]=f2bf(a[2]); o[3]=f2bf(a[3]);
    o[4]=f2bf(b[0]); o[5]=f2bf(b[1]); o[6]=f2bf(b[2]); o[7]=f2bf(b[3]);
    ((u16x8*)dst)[i] = o;
}

__global__ __launch_bounds__(256) void cvt_w_kernel(
    const float* __restrict__ w0, const float* __restrict__ w1,
    const float* __restrict__ w2, const float* __restrict__ w3,
    u16* __restrict__ dst)   // 4 consecutive D*D segments: Wq,Wk,Wv,Wo
{
    const float* src = (blockIdx.y == 0) ? w0 : (blockIdx.y == 1) ? w1
                     : (blockIdx.y == 2) ? w2 : w3;
    u16* d = dst + (size_t)blockIdx.y * (D_ * D_);
    int i = blockIdx.x * 256 + threadIdx.x;
    f32x4 a = ((const f32x4*)src)[2 * i];
    f32x4 b = ((const f32x4*)src)[2 * i + 1];
    u16x8 o;
    o[0]=f2bf(a[0]); o[1]=f2bf(a[1]); o[2]=f2bf(a[2]); o[3]=f2bf(a[3]);
    o[4]=f2bf(b[0]); o[5]=f2bf(b[1]); o[6]=f2bf(b[2]); o[7]=f2bf(b[3]);
    ((u16x8*)d)[i] = o;
}

// ---------------------------------------------------------------------------
// QKV GEMM: C[M,N] = X[M,K] @ W[N,K]^T — 256x192 tile, 8 waves (2M x 4N),
// BK=64, 2 FAT PHASES per K-tile (round-7 verified: dropped 95.5us -> <80).
// ---------------------------------------------------------------------------
template<int OUT_MODE>
__global__ __launch_bounds__(512) void gemm8_kernel(
    const u16* __restrict__ X, const u16* __restrict__ W,
    void* __restrict__ C, int M, int N, int K)
{
    __shared__ __align__(16) u16 Ab2[2][256 * 64];   // 64 KB
    __shared__ __align__(16) u16 Bb2[2][192 * 64];   // 48 KB

    const int tid  = threadIdx.x;
    const int wave = tid >> 6;
    const int lane = tid & 63;
    const int lq = lane >> 4, lm = lane & 15;
    const int wm = wave >> 2;      // wave's M slot (0..1) -> 128 rows
    const int wn = wave & 3;       // wave's N slot (0..3) -> 48 cols

    // rect XCD swizzle: XCD (bid&7) owns an 8x8 tile rectangle
    const int xcd = (int)blockIdx.x & 7;
    const int idx = (int)blockIdx.x >> 3;   // 0..63
    const int m0 = (((xcd & 3) << 3) + (idx & 7)) << 8;      // 32 M-tiles
    const int n0 = (((xcd >> 2) << 3) + (idx >> 3)) * 192;   // 16 N-tiles

    // staging: each gl2lds covers 64 rows (512thr x 16B = 8KB); 16B chunk
    // scol pre-swizzled so LINEAR LDS DMA writes land in swizzled layout.
    const int srow = wave * 8 + (lane >> 3);                 // 0..63
    const int scol = ((lane & 7) ^ (lane >> 3)) << 3;        // elements
    const u16* gA = X + (size_t)(m0 + srow) * K + scol;
    const u16* gB = W + (size_t)(n0 + srow) * K + scol;
    const size_t rK64 = (size_t)64 * K;

    const int swzr = (lm & 7) << 4;        // ds_read byte-address XOR

    f32x4 acc[8][3] = {};                  // 96 AGPR
    const int NT = K >> 6;                 // 16

    // ---- prologue: stage A0(4), B0(3), B1(3) ----
    gl2lds16(gA,            (u16*)Ab2[0] + wave * 512);
    gl2lds16(gA + rK64,     (u16*)Ab2[0] + 4096  + wave * 512);
    gl2lds16(gA + 2 * rK64, (u16*)Ab2[0] + 8192  + wave * 512);
    gl2lds16(gA + 3 * rK64, (u16*)Ab2[0] + 12288 + wave * 512);
    gl2lds16(gB,            (u16*)Bb2[0] + wave * 512);
    gl2lds16(gB + rK64,     (u16*)Bb2[0] + 4096  + wave * 512);
    gl2lds16(gB + 2 * rK64, (u16*)Bb2[0] + 8192  + wave * 512);
    gl2lds16(gB + 64,            (u16*)Bb2[1] + wave * 512);
    gl2lds16(gB + 64 + rK64,     (u16*)Bb2[1] + 4096  + wave * 512);
    gl2lds16(gB + 64 + 2 * rK64, (u16*)Bb2[1] + 8192  + wave * 512);
    VMCNT(3);                               // A0,B0 landed; B1 (3) in flight
    __builtin_amdgcn_s_barrier();

#define MFMA_HALF(IOFF)                                                     \
        __builtin_amdgcn_s_setprio(1);                                      \
        _Pragma("unroll")                                                   \
        for (int ks = 0; ks < 2; ++ks)                                      \
            _Pragma("unroll")                                               \
            for (int i4 = 0; i4 < 4; ++i4)                                  \
                _Pragma("unroll")                                           \
                for (int j = 0; j < 3; ++j)                                 \
                    acc[(IOFF) + i4][j] =                                   \
                        __builtin_amdgcn_mfma_f32_16x16x32_bf16(            \
                            af[i4][ks], bq[j][ks], acc[(IOFF) + i4][j],     \
                            0, 0, 0);                                       \
        __builtin_amdgcn_s_setprio(0);

#pragma unroll 1
    for (int t = 0; t < NT; ++t) {
        const u16* Ac = Ab2[t & 1];
        const u16* Bc = Bb2[t & 1];
        u16* Abn = (u16*)Ab2[(t + 1) & 1];
        u16* Bbc = (u16*)Bb2[t & 1];
        const bool stA = (t + 1 < NT);
        const bool stB = (t + 2 < NT);
        const u16* gAs = gA + (size_t)(t + 1) * 64;
        const u16* gBs = gB + (size_t)(t + 2) * 64;

        bf16x8 af[4][2], bq[3][2];

        // ---- P0: quadrants i=0..3; bq for whole tile ----
#pragma unroll
        for (int i4 = 0; i4 < 4; ++i4)
#pragma unroll
            for (int ks = 0; ks < 2; ++ks)
                af[i4][ks] = ldsrd(Ac, wm * 128 + i4 * 16 + lm, ks, lq, swzr);
#pragma unroll
        for (int j = 0; j < 3; ++j)
#pragma unroll
            for (int ks = 0; ks < 2; ++ks)
                bq[j][ks] = ldsrd(Bc, wn * 48 + j * 16 + lm, ks, lq, swzr);
        if (stA) {
            gl2lds16(gAs,        Abn + wave * 512);
            gl2lds16(gAs + rK64, Abn + 4096 + wave * 512);
        }
        SB0(); __builtin_amdgcn_s_barrier();
        LGKM0(); SB0();
        MFMA_HALF(0)
        SB0(); __builtin_amdgcn_s_barrier();

        // ---- P1: quadrants i=4..7 ----
#pragma unroll
        for (int i4 = 0; i4 < 4; ++i4)
#pragma unroll
            for (int ks = 0; ks < 2; ++ks)
                af[i4][ks] = ldsrd(Ac, wm * 128 + (4 + i4) * 16 + lm, ks, lq, swzr);
        if (stA) {
            gl2lds16(gAs + 2 * rK64, Abn + 8192  + wave * 512);
            gl2lds16(gAs + 3 * rK64, Abn + 12288 + wave * 512);
        }
        if (stB) {
            gl2lds16(gBs,            Bbc + wave * 512);
            gl2lds16(gBs + rK64,     Bbc + 4096 + wave * 512);
            gl2lds16(gBs + 2 * rK64, Bbc + 8192 + wave * 512);
        }
        SB0(); __builtin_amdgcn_s_barrier();
        LGKM0(); SB0();
        MFMA_HALF(4)
        SB0();
        if (stB)      { VMCNT(3); }   // A[t+1],B[t+1] landed; B[t+2] in flight
        else if (stA) { VMCNT(0); }   // t==NT-2: drain A[NT-1]
        __builtin_amdgcn_s_barrier();
    }
#undef MFMA_HALF

    // ---- epilogue: acc[i][j][r] -> row m0+wm*128+i*16+lq*4+r,
    //                               col n0+wn*48+j*16+lm ----
#pragma unroll
    for (int i = 0; i < 8; ++i)
#pragma unroll
        for (int j = 0; j < 3; ++j) {
            int rowb = m0 + wm * 128 + i * 16 + lq * 4;
            int col  = n0 + wn * 48 + j * 16 + lm;
            if (OUT_MODE == 2) {
#pragma unroll
                for (int r = 0; r < 4; ++r)
                    ((float*)C)[(size_t)(rowb + r) * N + col] = acc[i][j][r];
            } else {
                u16* Qp = (u16*)C;
                int region = col >> 10;      // per-fragment: 192 tile straddles
                int colr = col & 1023;
                if (region == 0) {
#pragma unroll
                    for (int r = 0; r < 4; ++r)
                        Qp[(size_t)(rowb + r) * D_ + colr] = f2bf(acc[i][j][r] * QSCALE);
                } else if (region == 1) {
#pragma unroll
                    for (int r = 0; r < 4; ++r)
                        (Qp + NT_)[(size_t)(rowb + r) * D_ + colr] = f2bf(acc[i][j][r]);
                } else {
                    int b = rowb >> 11, tt2 = rowb & (T_ - 1);   // 4 consecutive t
                    u16x4 pk;
#pragma unroll
                    for (int r = 0; r < 4; ++r) pk[r] = f2bf(acc[i][j][r]);
                    *(u16x4*)((Qp + 2 * NT_) + ((size_t)b * D_ + colr) * T_ + tt2) = pk;
                }
            }
        }
}

// ---------------------------------------------------------------------------
// Out-projection GEMM: 256x128 tile, 8 waves, read-pipelined 4-phase
// schedule (unchanged — not in top-5).
// ---------------------------------------------------------------------------
__global__ __launch_bounds__(512) void gemm8o_kernel(
    const u16* __restrict__ X, const u16* __restrict__ W,
    float* __restrict__ C)    // M=8192, N=1024, K=1024
{
    __shared__ __align__(16) u16 Ab2[2][256 * 64];   // 64 KB
    __shared__ __align__(16) u16 Bb2[2][128 * 64];   // 32 KB

    const int K = 1024, N = 1024;
    const int tid  = threadIdx.x;
    const int wave = tid >> 6;
    const int lane = tid & 63;
    const int lq = lane >> 4, lm = lane & 15;
    const int wm = wave >> 2;      // 0..1 -> 128 rows
    const int wn = wave & 3;       // 0..3 -> 32 cols

    // rect XCD swizzle: XCD owns an 8x4 tile rectangle (32 M-tiles, 8 N-tiles)
    const int xcd = (int)blockIdx.x & 7;
    const int idx = (int)blockIdx.x >> 3;   // 0..31
    const int m0 = (((xcd & 3) << 3) + (idx & 7)) << 8;
    const int n0 = (((xcd >> 2) << 2) + (idx >> 3)) << 7;

    const int srow = wave * 8 + (lane >> 3);                 // 0..63
    const int scol = ((lane & 7) ^ (lane >> 3)) << 3;        // elements
    const u16* gA = X + (size_t)(m0 + srow) * K + scol;
    const u16* gB = W + (size_t)(n0 + srow) * K + scol;
    const size_t rK64 = (size_t)64 * K;

    const int swzr = (lm & 7) << 4;

    f32x4 acc[8][2] = {};                  // 64 AGPR
    bf16x8 afA[2][2], afB[2][2];
    bf16x8 bqA[2][2], bqB[2][2];
    const int NT = 16;

    // ---- prologue: stage A0(4), B0(2), B1(2) ----
    gl2lds16(gA,            (u16*)Ab2[0] + wave * 512);
    gl2lds16(gA + rK64,     (u16*)Ab2[0] + 4096  + wave * 512);
    gl2lds16(gA + 2 * rK64, (u16*)Ab2[0] + 8192  + wave * 512);
    gl2lds16(gA + 3 * rK64, (u16*)Ab2[0] + 12288 + wave * 512);
    gl2lds16(gB,            (u16*)Bb2[0] + wave * 512);
    gl2lds16(gB + rK64,     (u16*)Bb2[0] + 4096  + wave * 512);
    gl2lds16(gB + 64,            (u16*)Bb2[1] + wave * 512);
    gl2lds16(gB + 64 + rK64,     (u16*)Bb2[1] + 4096  + wave * 512);
    VMCNT(2);                               // A0,B0 landed; B1 (2) in flight
    __builtin_amdgcn_s_barrier();
#pragma unroll
    for (int i2 = 0; i2 < 2; ++i2)
#pragma unroll
        for (int ks = 0; ks < 2; ++ks)
            afA[i2][ks] = ldsrd(Ab2[0], wm * 128 + i2 * 16 + lm, ks, lq, swzr);
#pragma unroll
    for (int j = 0; j < 2; ++j)
#pragma unroll
        for (int ks = 0; ks < 2; ++ks)
            bqA[j][ks] = ldsrd(Bb2[0], wn * 32 + j * 16 + lm, ks, lq, swzr);

    auto tile_body = [&](int t, bf16x8 (&bqU)[2][2], bf16x8 (&bqF)[2][2])
        __attribute__((always_inline)) -> void {
        const u16* Ac = Ab2[t & 1];
        const u16* An = Ab2[(t + 1) & 1];
        const u16* Bn = Bb2[(t + 1) & 1];
        u16* Abn = (u16*)Ab2[(t + 1) & 1];
        u16* Bbc = (u16*)Bb2[t & 1];
        const bool stA = (t + 1 < NT);
        const bool stB = (t + 2 < NT);
        const u16* gAs = gA + (size_t)(t + 1) * 64;
        const u16* gBs = gB + (size_t)(t + 2) * 64;

#define MFMA_PHO(Q, AF, BQ)                                                 \
        __builtin_amdgcn_s_setprio(1);                                      \
        _Pragma("unroll")                                                   \
        for (int ks = 0; ks < 2; ++ks)                                      \
            _Pragma("unroll")                                               \
            for (int i2 = 0; i2 < 2; ++i2)                                  \
                _Pragma("unroll")                                           \
                for (int j = 0; j < 2; ++j)                                 \
                    acc[2 * (Q) + i2][j] =                                   \
                        __builtin_amdgcn_mfma_f32_16x16x32_bf16(            \
                            AF[i2][ks], BQ[j][ks], acc[2 * (Q) + i2][j],    \
                            0, 0, 0);                                       \
        __builtin_amdgcn_s_setprio(0);

#define RD_AFO(SET, P, BASE)                                                \
        _Pragma("unroll")                                                   \
        for (int i2 = 0; i2 < 2; ++i2)                                      \
            _Pragma("unroll")                                               \
            for (int ks = 0; ks < 2; ++ks)                                  \
                SET[i2][ks] = ldsrd(BASE,                                   \
                    wm * 128 + (2 * (P) + i2) * 16 + lm, ks, lq, swzr);

        // ---- phase 0 ----
        RD_AFO(afB, 1, Ac);
        if (stA) {
            gl2lds16(gAs,        Abn + wave * 512);
            gl2lds16(gAs + rK64, Abn + 4096 + wave * 512);
        }
        SB0(); __builtin_amdgcn_s_barrier(); SB0();
        MFMA_PHO(0, afA, bqU); SB0();
        __builtin_amdgcn_s_barrier();

        // ---- phase 1 ----
        RD_AFO(afA, 2, Ac);
        if (stA) {
            gl2lds16(gAs + 2 * rK64, Abn + 8192  + wave * 512);
            gl2lds16(gAs + 3 * rK64, Abn + 12288 + wave * 512);
        }
        SB0(); __builtin_amdgcn_s_barrier(); SB0();
        MFMA_PHO(1, afB, bqU); SB0();
        __builtin_amdgcn_s_barrier();

        // ---- phase 2 ----
        RD_AFO(afB, 3, Ac);
        if (stB)
            gl2lds16(gBs, Bbc + wave * 512);
        SB0(); __builtin_amdgcn_s_barrier(); SB0();
        MFMA_PHO(2, afA, bqU); SB0();
        if (stB)      { VMCNT(1); }   // B[t+1]+A[t+1] landed; B[t+2]h0 in flight
        else if (stA) { VMCNT(0); }   // t==NT-2: drain A[NT-1] (+B tail)
        __builtin_amdgcn_s_barrier();

        // ---- phase 3 ----
        if (stA) {
            RD_AFO(afA, 0, An);
#pragma unroll
            for (int j = 0; j < 2; ++j)
#pragma unroll
                for (int ks = 0; ks < 2; ++ks)
                    bqF[j][ks] = ldsrd(Bn, wn * 32 + j * 16 + lm, ks, lq, swzr);
        }
        if (stB)
            gl2lds16(gBs + rK64, Bbc + 4096 + wave * 512);
        SB0(); __builtin_amdgcn_s_barrier(); SB0();
        MFMA_PHO(3, afB, bqU); SB0();
        __builtin_amdgcn_s_barrier();
#undef RD_AFO
#undef MFMA_PHO
    };

#pragma unroll 1
    for (int tt = 0; tt < NT; tt += 2) {
        tile_body(tt,     bqA, bqB);
        tile_body(tt + 1, bqB, bqA);
    }

    // ---- epilogue: fp32 natural ----
#pragma unroll
    for (int i = 0; i < 8; ++i)
#pragma unroll
        for (int j = 0; j < 2; ++j) {
            int rowb = m0 + wm * 128 + i * 16 + lq * 4;
            int col  = n0 + wn * 32 + j * 16 + lm;
#pragma unroll
            for (int r = 0; r < 4; ++r)
                C[(size_t)(rowb + r) * N + col] = acc[i][j][r];
        }
}

// ---------------------------------------------------------------------------
// Flash causal attention — round-4 structure + setprio; ROUND-8 change:
// V loads HOISTED to the top of each 32-key chunk, before the K loads.
// In-order vmcnt retirement means t0's K-wait covers V too (V issued
// earlier, same latency path) -> PV's ~200-250cy V-wait disappears from
// the per-chunk serial chain (~720cy). Costs ~12 VGPR held across
// QK+softmax; round-7 measured VGPR=112, so this fits under the 128
// occupancy step (round-5 lesson: >128 halves occupancy -> abort signal).
// ---------------------------------------------------------------------------
__global__ __launch_bounds__(128) void attn_kernel(
    const u16* __restrict__ Qg, const u16* __restrict__ Kg,
    const u16* __restrict__ Vtg, u16* __restrict__ Og)
{
    __shared__ __align__(16) u16 Pl[2 * 64 * 40];    // 10.25KB; reused for combine

    const int tid  = threadIdx.x;
    const int wave = tid >> 6;
    const int lane = tid & 63;
    const int lq = lane >> 4, lm = lane & 15;
    const int id = blockIdx.x;            // 0..2047
    const int xs = id & 7;                // XCD slot
    const int bh = xs + 8 * ((id >> 3) & 7);   // 8 bh per XCD slot
    const int qj = 31 - (id >> 6);        // longest-first dispatch order
    const int b = bh >> 4, h = bh & 15;

    const size_t batchoff = (size_t)b * T_ * D_;
    const size_t headoff  = (size_t)h * DH_;
    const size_t vbase    = (size_t)bh * DH_ * T_;

    u16* pw = Pl + wave * 64 * 40;

    const int qw  = qj * 64;
    const int ktd = qj >> 1;               // diagonal 128-key tile
    const int odd = qj & 1;                // which half of diag tile

    // Q fragments (B-operand): lane holds query qw+qf*16+lm, dh=ks*32+lq*8+j
    bf16x8 aq[4][2];
#pragma unroll
    for (int qf = 0; qf < 4; ++qf) {
        const u16* qrow = Qg + batchoff + (size_t)(qw + qf * 16 + lm) * D_ + headoff;
        aq[qf][0] = *(const bf16x8*)(qrow + lq * 8);
        aq[qf][1] = *(const bf16x8*)(qrow + 32 + lq * 8);
    }

    f32x4 oaccT[4][4] = {};          // [qf][dh-frag]; row=dh, col=query
    float l_lane[4] = {0.f, 0.f, 0.f, 0.f};

    // split-K: wave w handles k-tiles of parity w
#pragma unroll 1
    for (int kt = wave; kt <= ktd; kt += 2) {
        const bool diag = (kt == ktd);
        const int ksmax = diag ? (odd ? 3 : 1) : 3;   // 32-key chunks

#pragma unroll
        for (int c = 0; c < 4; ++c) {
            if (c <= ksmax) {
                // ---- V loads FIRST: issued before K, so the K-wait covers
                //      them; by PV time they are in registers, zero wait ----
                bf16x8 vf[4];
#pragma unroll
                for (int mo = 0; mo < 4; ++mo) {
                    const u16* vrow = Vtg + vbase
                        + (size_t)(mo * 16 + lm) * T_ + kt * 128 + c * 32;
                    vf[mo] = *(const bf16x8*)(vrow + lq * 8);
                }

                // ---- two 16-key fragments: S^T mfma -> mask -> exp2 -> pack ----
#pragma unroll
                for (int t = 0; t < 2; ++t) {
                    const int mt = 2 * c + t;
                    const u16* krow = Kg + batchoff
                        + (size_t)(kt * 128 + mt * 16 + lm) * D_ + headoff;
                    bf16x8 kf0 = *(const bf16x8*)(krow + lq * 8);
                    bf16x8 kf1 = *(const bf16x8*)(krow + 32 + lq * 8);
                    f32x4 s[4];
                    __builtin_amdgcn_s_setprio(1);
#pragma unroll
                    for (int qf = 0; qf < 4; ++qf) {
                        s[qf] = f32x4{0.f, 0.f, 0.f, 0.f};
                        s[qf] = __builtin_amdgcn_mfma_f32_16x16x32_bf16(
                            kf0, aq[qf][0], s[qf], 0, 0, 0);
                        s[qf] = __builtin_amdgcn_mfma_f32_16x16x32_bf16(
                            kf1, aq[qf][1], s[qf], 0, 0, 0);
                    }
                    __builtin_amdgcn_s_setprio(0);
                    if (diag) {
                        int keyb = kt * 128 + mt * 16 + lq * 4;
#pragma unroll
                        for (int qf = 0; qf < 4; ++qf) {
                            int query = qw + qf * 16 + lm;
#pragma unroll
                            for (int r = 0; r < 4; ++r)
                                if (keyb + r > query) s[qf][r] = -1e9f;
                        }
                    }
#pragma unroll
                    for (int qf = 0; qf < 4; ++qf) {
                        float p0 = __builtin_amdgcn_exp2f(s[qf][0]);
                        float p1 = __builtin_amdgcn_exp2f(s[qf][1]);
                        float p2 = __builtin_amdgcn_exp2f(s[qf][2]);
                        float p3 = __builtin_amdgcn_exp2f(s[qf][3]);
                        l_lane[qf] += (p0 + p1) + (p2 + p3);
                        uint2 d; d.x = pack2(p0, p1); d.y = pack2(p2, p3);
                        *(uint2*)(pw + (qf * 16 + lm) * 40 + t * 16 + lq * 4) = d;
                    }
                }
                // same-wave LDS RAW: compiler inserts lgkmcnt waits

                // ---- O^T += V^T P^T for this 32-key chunk ----
                bf16x8 pf[4];
#pragma unroll
                for (int qf = 0; qf < 4; ++qf)
                    pf[qf] = *(const bf16x8*)(pw + (qf * 16 + lm) * 40 + lq * 8);
                __builtin_amdgcn_s_setprio(1);
#pragma unroll
                for (int mo = 0; mo < 4; ++mo)
#pragma unroll
                    for (int qf = 0; qf < 4; ++qf)
                        oaccT[qf][mo] = __builtin_amdgcn_mfma_f32_16x16x32_bf16(
                            vf[mo], pf[qf], oaccT[qf][mo], 0, 0, 0);
                __builtin_amdgcn_s_setprio(0);
            }
        }
    }

    // ---- split-K combine through retired Pl (two 8-slot rounds) ----
    float* Cf = (float*)Pl;                      // 2560 floats
    const int cswz = (lane ^ (lane >> 3)) * 4;   // f32x4 float-offset in slot
    __syncthreads();                             // both waves done with Pl
    if (wave == 1) {
#pragma unroll
        for (int qf = 0; qf < 2; ++qf)
#pragma unroll
            for (int mo = 0; mo < 4; ++mo)
                *(f32x4*)&Cf[(qf * 4 + mo) * 256 + cswz] = oaccT[qf][mo];
#pragma unroll
        for (int qf = 0; qf < 4; ++qf)
            Cf[2048 + qf * 64 + lane] = l_lane[qf];   // l partials (1KB tail)
    }
    __syncthreads();
    if (wave == 0) {
#pragma unroll
        for (int qf = 0; qf < 2; ++qf)
#pragma unroll
            for (int mo = 0; mo < 4; ++mo) {
                f32x4 o = *(const f32x4*)&Cf[(qf * 4 + mo) * 256 + cswz];
#pragma unroll
                for (int r = 0; r < 4; ++r) oaccT[qf][mo][r] += o[r];
            }
#pragma unroll
        for (int qf = 0; qf < 4; ++qf) l_lane[qf] += Cf[2048 + qf * 64 + lane];
    }
    __syncthreads();
    if (wave == 1) {
#pragma unroll
        for (int qf = 2; qf < 4; ++qf)
#pragma unroll
            for (int mo = 0; mo < 4; ++mo)
                *(f32x4*)&Cf[((qf - 2) * 4 + mo) * 256 + cswz] = oaccT[qf][mo];
    }
    __syncthreads();
    if (wave == 0) {
#pragma unroll
        for (int qf = 2; qf < 4; ++qf)
#pragma unroll
            for (int mo = 0; mo < 4; ++mo) {
                f32x4 o = *(const f32x4*)&Cf[((qf - 2) * 4 + mo) * 256 + cswz];
#pragma unroll
                for (int r = 0; r < 4; ++r) oaccT[qf][mo][r] += o[r];
            }
        // epilogue: reduce l across quads, O = O^T / l, packed stores
#pragma unroll
        for (int qf = 0; qf < 4; ++qf) {
            float l = l_lane[qf];
            l += __shfl_xor(l, 16, 64);
            l += __shfl_xor(l, 32, 64);
            float inv = 1.0f / l;
            int row = qw + qf * 16 + lm;
            u16* obase = Og + batchoff + (size_t)row * D_ + headoff;
#pragma unroll
            for (int mo = 0; mo < 4; ++mo) {
                uint2 d;
                d.x = pack2(oaccT[qf][mo][0] * inv, oaccT[qf][mo][1] * inv);
                d.y = pack2(oaccT[qf][mo][2] * inv, oaccT[qf][mo][3] * inv);
                *(uint2*)(obase + mo * 16 + lq * 4) = d;
            }
        }
    }
}

// ---------------------------------------------------------------------------
extern "C" void kernel_launch(void* const* d_in, const int* in_sizes, int n_in,
                              void* d_out, int out_size, void* d_ws, size_t ws_size,
                              hipStream_t stream)
{
    const float* x  = (const float*)d_in[0];   // fp32 (B,T,D)
    // d_in[1] = mask (int32 tril) — causality hardcoded, not read
    const float* Wq = (const float*)d_in[2];   // fp32 (D,D)
    const float* Wk = (const float*)d_in[3];
    const float* Wv = (const float*)d_in[4];
    const float* Wo = (const float*)d_in[5];

    const size_t DD = (size_t)D_ * D_;
    u16* Qb  = (u16*)d_ws;        // Q (scaled), K, V(trans) contiguous
    u16* Kb  = Qb + NT_;
    u16* Vb  = Kb + NT_;
    u16* Ob  = Vb + NT_;
    u16* xb  = Ob + NT_;
    u16* wb  = xb + NT_;          // 4 x DD: Wq, Wk, Wv, Wo

    const int M = B_ * T_;        // 8192

    cvt_x_kernel<<<dim3((int)(NT_ / 8 / 256)), 256, 0, stream>>>(x, xb, (int)(NT_ / 8));
    cvt_w_kernel<<<dim3((int)(DD / 8 / 256), 4), 256, 0, stream>>>(Wq, Wk, Wv, Wo, wb);

    // fused Q/K/V projection: x @ [Wq;Wk;Wv]^T, N=3072, routed epilogue
    // 256x192 tile, 8 waves, 2 fat phases/K-tile: grid = 32*16 = 512 blocks
    gemm8_kernel<3><<<dim3((M / 256) * (3 * D_ / 192)), 512, 0, stream>>>(
        xb, wb, Qb, M, 3 * D_, D_);

    // split-K (2 waves/block) attention: 2048 blocks x 128 thr (1 q-tile each),
    // longest-first, XCD-swizzled (round-4 structure + setprio + V-hoist)
    attn_kernel<<<dim3(2048), 128, 0, stream>>>(Qb, Kb, Vb, Ob);

    // output projection -> fp32: 256x128 tile, 256 blocks = 1 full round
    gemm8o_kernel<<<dim3(256), 512, 0, stream>>>(Ob, wb + 3 * DD, (float*)d_out);
}